// Round 5
// baseline (626.107 us; speedup 1.0000x reference)
//
#include <hip/hip_runtime.h>
#include <cstdint>
#include <cstddef>

typedef unsigned short u16;
typedef unsigned int u32;
typedef __attribute__((ext_vector_type(8))) short short8;
typedef __attribute__((ext_vector_type(4))) float f32x4;

#define T_SEQ 2048
#define BT_ROWS 16384

// ---------- helpers ----------
__device__ __forceinline__ u16 f2bf(float x) {
  union { float f; u32 u; } v; v.f = x;
  u32 r = v.u + 0x7fffu + ((v.u >> 16) & 1u);
  return (u16)(r >> 16);
}
// pack two floats -> two bf16 in one u32 (lo in low half)
__device__ __forceinline__ u32 pkbf(float lo, float hi) {
  union { float f; u32 u; } a, b; a.f = lo; b.f = hi;
  const u32 ra = a.u + 0x7fffu + ((a.u >> 16) & 1u);
  const u32 rb = b.u + 0x7fffu + ((b.u >> 16) & 1u);
  return __builtin_amdgcn_perm(rb, ra, 0x07060302);
}
__device__ __forceinline__ float wave_bcast_sum(float x) {
#pragma unroll
  for (int off = 32; off > 0; off >>= 1) x += __shfl_down(x, off);
  return __shfl(x, 0);
}
// tanh-form GELU; |diff| vs erf ~3e-4
__device__ __forceinline__ float gelu_f(float x) {
  float z = 1.5957691216057308f * x * (1.0f + 0.044715f * x * x);
  float e = __expf(z);
  return x - x * __builtin_amdgcn_rcpf(1.0f + e);
}

// ---------- transpose+convert all 3 weights + zero logits ----------
__global__ __launch_bounds__(256) void tcvt_all(const float* __restrict__ Wv,
                                                const float* __restrict__ Wa,
                                                const float* __restrict__ W1,
                                                u16* __restrict__ wvT,
                                                u16* __restrict__ waT,
                                                u16* __restrict__ w1T,
                                                float* __restrict__ logits) {
  int b = blockIdx.x;
  if (b >= 1216) {  // 64 blocks zero the 16384-float logits buffer
    logits[(b - 1216) * 256 + threadIdx.x] = 0.0f;
    return;
  }
  __shared__ float tile[32][33];
  const float* in; u16* out; int K, N, bx, by;
  if (b < 256)      { in = Wv; out = wvT; K = 1024; N = 256;  bx = b & 31;  by = b >> 5; }
  else if (b < 448) { b -= 256; in = Wa; out = waT; K = 768; N = 256;  bx = b % 24; by = b / 24; }
  else              { b -= 448; in = W1; out = w1T; K = 768; N = 1024; bx = b % 24; by = b / 24; }
  const int k0 = bx * 32, n0 = by * 32;
  const int tx = threadIdx.x & 31, ty = threadIdx.x >> 5;
#pragma unroll
  for (int r = 0; r < 4; r++)
    tile[ty + r * 8][tx] = in[(size_t)(k0 + ty + r * 8) * N + n0 + tx];
  __syncthreads();
#pragma unroll
  for (int r = 0; r < 4; r++)
    out[(size_t)(n0 + ty + r * 8) * K + k0 + tx] = f2bf(tile[tx][ty + r * 8]);
}

// ---------- merged projection GEMM, register-prefetch pipelined ----------
// C[M][256] f32 = A[M][K] f32 @ Bt[256][K] bf16^T. Tile 64x128, BK=64.
// Blocks 0..511: video (K=1024); 512..1023: audio (K=768).
__global__ __launch_bounds__(256, 4) void gemm_proj(const float* __restrict__ Vin,
                                                    const float* __restrict__ Ain,
                                                    const u16* __restrict__ wvT,
                                                    const u16* __restrict__ waT,
                                                    float* __restrict__ Cv,
                                                    float* __restrict__ Ca) {
  __shared__ float Asf[64 * 64];   // 16 KB
  __shared__ u16 Bs[128 * 64];     // 16 KB
  int b = blockIdx.x;
  const float* A; const u16* Bt; float* C; int K;
  if (b < 512) { A = Vin; Bt = wvT; C = Cv; K = 1024; }
  else         { b -= 512; A = Ain; Bt = waT; C = Ca; K = 768; }
  const int m0 = (b >> 1) * 64;
  const int n0 = (b & 1) * 128;
  const int tid = threadIdx.x;
  const int wave = tid >> 6, lane = tid & 63, qm = lane & 15, quad = lane >> 4;
  const int rw = (wave >> 1) * 32, cw = (wave & 1) * 64;

  // same verified swizzled chunk layout as r4; only the path to LDS changed
  const int arow = tid >> 4;
  const int apart = (tid & 15) ^ (arow & 15);
  const float* Ap[4];
#pragma unroll
  for (int g = 0; g < 4; g++)
    Ap[g] = A + (size_t)(m0 + arow + g * 16) * K + apart * 4;
  const int brow = tid >> 3;
  const int bpart = (tid & 7) ^ (brow & 7);
  const u16* Bp[4];
#pragma unroll
  for (int g = 0; g < 4; g++)
    Bp[g] = Bt + (size_t)(n0 + brow + g * 32) * K + bpart * 8;

  // preload tile 0 into registers
  float4 aReg[4]; uint4 bReg[4];
#pragma unroll
  for (int g = 0; g < 4; g++) aReg[g] = *(const float4*)(Ap[g]);
#pragma unroll
  for (int g = 0; g < 4; g++) bReg[g] = *(const uint4*)(Bp[g]);

  f32x4 acc[2][4] = {};
  for (int kt = 0; kt < K; kt += 64) {
    // drain regs -> LDS (prev compute finished at loop-bottom barrier)
#pragma unroll
    for (int g = 0; g < 4; g++) *(float4*)&Asf[(tid + g * 256) * 4] = aReg[g];
#pragma unroll
    for (int g = 0; g < 4; g++) *(uint4*)&Bs[(tid + g * 256) * 8] = bReg[g];
    // issue next tile's loads; they stay in flight across barrier+compute
    if (kt + 64 < K) {
#pragma unroll
      for (int g = 0; g < 4; g++) aReg[g] = *(const float4*)(Ap[g] + kt + 64);
#pragma unroll
      for (int g = 0; g < 4; g++) bReg[g] = *(const uint4*)(Bp[g] + kt + 64);
    }
    __syncthreads();
#pragma unroll
    for (int s = 0; s < 2; s++) {
      short8 af[2], bfr[4];
#pragma unroll
      for (int i = 0; i < 2; i++) {
        const int r = rw + i * 16 + qm;
        const int pb = s * 8 + quad * 2;
        const float4 f0 = *(const float4*)&Asf[r * 64 + ((pb) ^ (r & 15)) * 4];
        const float4 f1 = *(const float4*)&Asf[r * 64 + ((pb + 1) ^ (r & 15)) * 4];
        u32 w[4] = {pkbf(f0.x, f0.y), pkbf(f0.z, f0.w), pkbf(f1.x, f1.y), pkbf(f1.z, f1.w)};
        af[i] = *(short8*)w;
      }
#pragma unroll
      for (int j = 0; j < 4; j++) {
        const int r = cw + j * 16 + qm;
        bfr[j] = *(const short8*)&Bs[r * 64 + ((s * 4 + quad) ^ (r & 7)) * 8];
      }
#pragma unroll
      for (int i = 0; i < 2; i++)
#pragma unroll
        for (int j = 0; j < 4; j++)
          acc[i][j] = __builtin_amdgcn_mfma_f32_16x16x32_bf16(af[i], bfr[j], acc[i][j], 0, 0, 0);
    }
    __syncthreads();
  }
#pragma unroll
  for (int i = 0; i < 2; i++) {
    const int row = m0 + rw + i * 16 + quad * 4;
#pragma unroll
    for (int j = 0; j < 4; j++) {
      const int col = n0 + cw + j * 16 + qm;
#pragma unroll
      for (int r = 0; r < 4; r++)
        C[(size_t)(row + r) * 256 + col] = acc[i][j][r];
    }
  }
}

// ---------- MLP GEMM, register-prefetch pipelined, fused bias+GELU+W2 -> atomic logits ----------
__global__ __launch_bounds__(256, 4) void gemm_gelu_w2(const u16* __restrict__ Axb,
                                                       const u16* __restrict__ Bt,
                                                       const float* __restrict__ b1,
                                                       const float* __restrict__ W2,
                                                       float* __restrict__ logits) {
  constexpr int K = 768;
  __shared__ u16 As[64 * 64];    // 8 KB
  __shared__ u16 Bs[128 * 64];   // 16 KB
  const int tid = threadIdx.x;
  const int n0 = blockIdx.x * 128;
  const int m0 = blockIdx.y * 64;
  const int wave = tid >> 6, lane = tid & 63, qm = lane & 15, quad = lane >> 4;
  const int rw = (wave >> 1) * 32, cw = (wave & 1) * 64;

  const int crow = tid >> 3;
  const int cpart = (tid & 7) ^ (crow & 7);
  const u16* Ap[2];
#pragma unroll
  for (int g = 0; g < 2; g++)
    Ap[g] = Axb + (size_t)(m0 + crow + g * 32) * K + cpart * 8;
  const u16* Bp[4];
#pragma unroll
  for (int g = 0; g < 4; g++)
    Bp[g] = Bt + (size_t)(n0 + crow + g * 32) * K + cpart * 8;

  uint4 aReg[2], bReg[4];
#pragma unroll
  for (int g = 0; g < 2; g++) aReg[g] = *(const uint4*)(Ap[g]);
#pragma unroll
  for (int g = 0; g < 4; g++) bReg[g] = *(const uint4*)(Bp[g]);

  f32x4 acc[2][4] = {};
  for (int kt = 0; kt < K; kt += 64) {
#pragma unroll
    for (int g = 0; g < 2; g++) *(uint4*)&As[(tid + g * 256) * 8] = aReg[g];
#pragma unroll
    for (int g = 0; g < 4; g++) *(uint4*)&Bs[(tid + g * 256) * 8] = bReg[g];
    if (kt + 64 < K) {
#pragma unroll
      for (int g = 0; g < 2; g++) aReg[g] = *(const uint4*)(Ap[g] + kt + 64);
#pragma unroll
      for (int g = 0; g < 4; g++) bReg[g] = *(const uint4*)(Bp[g] + kt + 64);
    }
    __syncthreads();
#pragma unroll
    for (int s = 0; s < 2; s++) {
      short8 af[2], bfr[4];
#pragma unroll
      for (int i = 0; i < 2; i++) {
        const int r = rw + i * 16 + qm;
        af[i] = *(const short8*)&As[r * 64 + ((s * 4 + quad) ^ (r & 7)) * 8];
      }
#pragma unroll
      for (int j = 0; j < 4; j++) {
        const int r = cw + j * 16 + qm;
        bfr[j] = *(const short8*)&Bs[r * 64 + ((s * 4 + quad) ^ (r & 7)) * 8];
      }
#pragma unroll
      for (int i = 0; i < 2; i++)
#pragma unroll
        for (int j = 0; j < 4; j++)
          acc[i][j] = __builtin_amdgcn_mfma_f32_16x16x32_bf16(af[i], bfr[j], acc[i][j], 0, 0, 0);
    }
    __syncthreads();
  }

  float w2j[4], bc[4];
#pragma unroll
  for (int j = 0; j < 4; j++) {
    const int col = n0 + cw + j * 16 + qm;
    w2j[j] = W2[col];
    bc[j] = b1[col];
  }
#pragma unroll
  for (int i = 0; i < 2; i++) {
#pragma unroll
    for (int r = 0; r < 4; r++) {
      float p = 0.0f;
#pragma unroll
      for (int j = 0; j < 4; j++)
        p += gelu_f(acc[i][j][r] + bc[j]) * w2j[j];
      p += __shfl_xor(p, 1);
      p += __shfl_xor(p, 2);
      p += __shfl_xor(p, 4);
      p += __shfl_xor(p, 8);
      if (qm == 0)
        atomicAdd(&logits[m0 + rw + i * 16 + quad * 4 + r], p);
    }
  }
}

// ---------- layernorm (bias added first) over both v and a ----------
__global__ __launch_bounds__(256) void ln2(float* __restrict__ v, float* __restrict__ a,
                                           const float* __restrict__ bv,
                                           const float* __restrict__ ba) {
  const int gr = blockIdx.x * 4 + (threadIdx.x >> 6);
  const int lane = threadIdx.x & 63;
  float* X; const float* bias; int row;
  if (gr < BT_ROWS) { X = v; bias = bv; row = gr; }
  else              { X = a; bias = ba; row = gr - BT_ROWS; }
  float4 x = *(float4*)&X[(size_t)row * 256 + lane * 4];
  const float4 b = *(const float4*)&bias[lane * 4];
  x.x += b.x; x.y += b.y; x.z += b.z; x.w += b.w;
  float s = x.x + x.y + x.z + x.w;
  float s2 = x.x * x.x + x.y * x.y + x.z * x.z + x.w * x.w;
  s = wave_bcast_sum(s);
  s2 = wave_bcast_sum(s2);
  const float mu = s * (1.0f / 256.0f);
  const float var = s2 * (1.0f / 256.0f) - mu * mu;
  const float inv = rsqrtf(var + 1e-5f);
  x.x = (x.x - mu) * inv; x.y = (x.y - mu) * inv;
  x.z = (x.z - mu) * inv; x.w = (x.w - mu) * inv;
  *(float4*)&X[(size_t)row * 256 + lane * 4] = x;
}

// ---------- fused: fractional shift + window avg + l2norm(actx,v) + concat ----------
__global__ __launch_bounds__(256) void shift_norm(const float* __restrict__ a,
                                                  const float* __restrict__ v,
                                                  float* __restrict__ actx,
                                                  u16* __restrict__ xb,
                                                  const float* __restrict__ theta) {
  const int row = blockIdx.x * 4 + (threadIdx.x >> 6);
  const int lane = threadIdx.x & 63;
  const int d4 = lane * 4;
  const int bb = row >> 11;
  const int t = row & (T_SEQ - 1);
  const float th = fminf(fmaxf(theta[0], -12.0f), 12.0f);
  const float delta = 2.0f + 4.0f * (1.0f / (1.0f + expf(-th)));
  const float dl = fminf(fmaxf(delta, 0.0f), (float)(T_SEQ - 1));
  const float nf = floorf(dl);
  const float alpha = dl - nf;
  const int ni = (int)nf;
  const float center = fminf(fmaxf((float)t + delta, 0.0f), (float)t);
  float sx = 0, sy = 0, sz = 0, sw = 0, cnt = 0.0f;
  const float* ab = a + (size_t)bb * T_SEQ * 256;
#pragma unroll
  for (int j = 0; j < 6; j++) {
    const int tau = t - 5 + j;
    if (tau < 0) continue;
    if (fabsf((float)tau - center) > 5.0f) continue;
    cnt += 1.0f;
    const int i0 = min(max(tau - ni, 0), T_SEQ - 1);
    const int i1 = min(i0 + 1, T_SEQ - 1);
    const float4 a0 = *(const float4*)&ab[(size_t)i0 * 256 + d4];
    const float4 a1 = *(const float4*)&ab[(size_t)i1 * 256 + d4];
    sx += a0.x + alpha * (a1.x - a0.x);
    sy += a0.y + alpha * (a1.y - a0.y);
    sz += a0.z + alpha * (a1.z - a0.z);
    sw += a0.w + alpha * (a1.w - a0.w);
  }
  const float sc = 1.0f / fmaxf(cnt, 1e-8f);
  float4 o; o.x = sx * sc; o.y = sy * sc; o.z = sz * sc; o.w = sw * sc;
  *(float4*)&actx[(size_t)row * 256 + d4] = o;
  const float4 vv = *(const float4*)&v[(size_t)row * 256 + d4];
  float sa2 = o.x * o.x + o.y * o.y + o.z * o.z + o.w * o.w;
  float sv2 = vv.x * vv.x + vv.y * vv.y + vv.z * vv.z + vv.w * vv.w;
  sa2 = wave_bcast_sum(sa2);
  sv2 = wave_bcast_sum(sv2);
  const float ia = 1.0f / fmaxf(sqrtf(sa2), 1e-8f);
  const float iv = 1.0f / fmaxf(sqrtf(sv2), 1e-8f);
  const float anx = o.x * ia, any_ = o.y * ia, anz = o.z * ia, anw = o.w * ia;
  const float vnx = vv.x * iv, vny = vv.y * iv, vnz = vv.z * iv, vnw = vv.w * iv;
  u16* xr = xb + (size_t)row * 768;
  u32 pa[2] = {pkbf(anx, any_), pkbf(anz, anw)};
  u32 pv[2] = {pkbf(vnx, vny), pkbf(vnz, vnw)};
  u32 pp[2] = {pkbf(anx * vnx, any_ * vny), pkbf(anz * vnz, anw * vnw)};
  *(uint2*)&xr[d4] = *(uint2*)pa;
  *(uint2*)&xr[256 + d4] = *(uint2*)pv;
  *(uint2*)&xr[512 + d4] = *(uint2*)pp;
}

// ---------- gate + mix ----------
__global__ __launch_bounds__(256) void gate_mix(const float* __restrict__ logits,
                                                const float* __restrict__ b2,
                                                const float* __restrict__ actx,
                                                const float* __restrict__ v,
                                                float* __restrict__ out) {
  const int row = blockIdx.x * 4 + (threadIdx.x >> 6);
  const int lane = threadIdx.x & 63;
  const float l = fminf(fmaxf(logits[row] + b2[0], -12.0f), 12.0f);
  float g = 1.0f / (1.0f + expf(-l));
  g = fminf(fmaxf(g, 0.05f), 0.95f);
  const float4 aa = *(const float4*)&actx[(size_t)row * 256 + lane * 4];
  const float4 vv = *(const float4*)&v[(size_t)row * 256 + lane * 4];
  float4 o;
  o.x = g * aa.x + (1.0f - g) * vv.x;
  o.y = g * aa.y + (1.0f - g) * vv.y;
  o.z = g * aa.z + (1.0f - g) * vv.z;
  o.w = g * aa.w + (1.0f - g) * vv.w;
  *(float4*)&out[(size_t)row * 256 + lane * 4] = o;
}

// ---------- launch ----------
extern "C" void kernel_launch(void* const* d_in, const int* in_sizes, int n_in,
                              void* d_out, int out_size, void* d_ws, size_t ws_size,
                              hipStream_t stream) {
  const float* video = (const float*)d_in[0];
  const float* audio = (const float*)d_in[1];
  const float* Wv    = (const float*)d_in[2];
  const float* bv    = (const float*)d_in[3];
  const float* Wa    = (const float*)d_in[4];
  const float* ba    = (const float*)d_in[5];
  const float* theta = (const float*)d_in[6];
  const float* W1    = (const float*)d_in[7];
  const float* b1    = (const float*)d_in[8];
  const float* W2    = (const float*)d_in[9];
  const float* b2    = (const float*)d_in[10];
  float* out = (float*)d_out;
  char* ws = (char*)d_ws;

  const size_t OFF_WVT = 0;          // [256][1024] bf16
  const size_t OFF_WAT = 524288;     // [256][768]  bf16
  const size_t OFF_W1T = 917504;     // [1024][768] bf16
  const size_t OFF_LOG = 2490368;    // [16384] f32
  const size_t OFF_V   = 2555904;    // [16384][256] f32
  const size_t OFF_A   = 19333120;   // [16384][256] f32
  const size_t OFF_ACTX= 36110336;   // [16384][256] f32
  const size_t OFF_XB  = 52887552;   // [16384][768] bf16

  u16* wvT = (u16*)(ws + OFF_WVT);
  u16* waT = (u16*)(ws + OFF_WAT);
  u16* w1T = (u16*)(ws + OFF_W1T);
  float* logits = (float*)(ws + OFF_LOG);
  float* v    = (float*)(ws + OFF_V);
  float* a    = (float*)(ws + OFF_A);
  float* actx = (float*)(ws + OFF_ACTX);
  u16* xb = (u16*)(ws + OFF_XB);

  tcvt_all<<<1280, 256, 0, stream>>>(Wv, Wa, W1, wvT, waT, w1T, logits);
  gemm_proj<<<1024, 256, 0, stream>>>(video, audio, wvT, waT, v, a);
  ln2<<<2 * BT_ROWS / 4, 256, 0, stream>>>(v, a, bv, ba);
  shift_norm<<<BT_ROWS / 4, 256, 0, stream>>>(a, v, actx, xb, theta);
  gemm_gelu_w2<<<dim3(8, BT_ROWS / 64), 256, 0, stream>>>(xb, w1T, b1, W2, logits);
  gate_mix<<<BT_ROWS / 4, 256, 0, stream>>>(logits, b2, actx, v, out);
}

// Round 6
// 414.031 us; speedup vs baseline: 1.5122x; 1.5122x over previous
//
#include <hip/hip_runtime.h>
#include <cstdint>
#include <cstddef>

typedef unsigned short u16;
typedef unsigned int u32;
typedef __attribute__((ext_vector_type(8))) short short8;
typedef __attribute__((ext_vector_type(4))) float f32x4;

#define T_SEQ 2048
#define BT_ROWS 16384

// ---------- helpers ----------
__device__ __forceinline__ u16 f2bf(float x) {
  union { float f; u32 u; } v; v.f = x;
  u32 r = v.u + 0x7fffu + ((v.u >> 16) & 1u);
  return (u16)(r >> 16);
}
// pack two floats -> two bf16 in one u32 (lo in low half)
__device__ __forceinline__ u32 pkbf(float lo, float hi) {
  union { float f; u32 u; } a, b; a.f = lo; b.f = hi;
  const u32 ra = a.u + 0x7fffu + ((a.u >> 16) & 1u);
  const u32 rb = b.u + 0x7fffu + ((b.u >> 16) & 1u);
  return __builtin_amdgcn_perm(rb, ra, 0x07060302);
}
__device__ __forceinline__ float wave_bcast_sum(float x) {
#pragma unroll
  for (int off = 32; off > 0; off >>= 1) x += __shfl_down(x, off);
  return __shfl(x, 0);
}
// tanh-form GELU; |diff| vs erf ~3e-4
__device__ __forceinline__ float gelu_f(float x) {
  float z = 1.5957691216057308f * x * (1.0f + 0.044715f * x * x);
  float e = __expf(z);
  return x - x * __builtin_amdgcn_rcpf(1.0f + e);
}

// ---------- transpose+convert all 3 weights + zero logits ----------
__global__ __launch_bounds__(256) void tcvt_all(const float* __restrict__ Wv,
                                                const float* __restrict__ Wa,
                                                const float* __restrict__ W1,
                                                u16* __restrict__ wvT,
                                                u16* __restrict__ waT,
                                                u16* __restrict__ w1T,
                                                float* __restrict__ logits) {
  int b = blockIdx.x;
  if (b >= 1216) {  // 64 blocks zero the 16384-float logits buffer
    logits[(b - 1216) * 256 + threadIdx.x] = 0.0f;
    return;
  }
  __shared__ float tile[32][33];
  const float* in; u16* out; int K, N, bx, by;
  if (b < 256)      { in = Wv; out = wvT; K = 1024; N = 256;  bx = b & 31;  by = b >> 5; }
  else if (b < 448) { b -= 256; in = Wa; out = waT; K = 768; N = 256;  bx = b % 24; by = b / 24; }
  else              { b -= 448; in = W1; out = w1T; K = 768; N = 1024; bx = b % 24; by = b / 24; }
  const int k0 = bx * 32, n0 = by * 32;
  const int tx = threadIdx.x & 31, ty = threadIdx.x >> 5;
#pragma unroll
  for (int r = 0; r < 4; r++)
    tile[ty + r * 8][tx] = in[(size_t)(k0 + ty + r * 8) * N + n0 + tx];
  __syncthreads();
#pragma unroll
  for (int r = 0; r < 4; r++)
    out[(size_t)(n0 + ty + r * 8) * K + k0 + tx] = f2bf(tile[tx][ty + r * 8]);
}

// ---------- merged projection GEMM, LDS-free (zero barriers) ----------
// C[M][256] f32 = A[M][K] f32 @ Bt[256][K] bf16^T. Block tile 64x128.
// Every lane loads its MFMA fragments directly from global; all reuse is
// in-register (A across j) or L1/L2 (B weights are L2-resident).
// Blocks 0..511: video (K=1024); 512..1023: audio (K=768).
__global__ __launch_bounds__(256) void gemm_proj(const float* __restrict__ Vin,
                                                 const float* __restrict__ Ain,
                                                 const u16* __restrict__ wvT,
                                                 const u16* __restrict__ waT,
                                                 float* __restrict__ Cv,
                                                 float* __restrict__ Ca) {
  int b = blockIdx.x;
  const float* A; const u16* Bt; float* C; int K;
  if (b < 512) { A = Vin; Bt = wvT; C = Cv; K = 1024; }
  else         { b -= 512; A = Ain; Bt = waT; C = Ca; K = 768; }
  const int m0 = (b >> 1) * 64;
  const int n0 = (b & 1) * 128;
  const int tid = threadIdx.x;
  const int wave = tid >> 6, lane = tid & 63, qm = lane & 15, quad = lane >> 4;
  const int rw = (wave >> 1) * 32, cw = (wave & 1) * 64;

  // A fragment rows: m0+rw+i*16+qm, k-chunk quad*8 (8 f32 = two float4)
  const float* Ar0 = A + (size_t)(m0 + rw + qm) * K + quad * 8;
  const float* Ar1 = Ar0 + (size_t)16 * K;
  // B fragment rows: n0+cw+j*16+qm, k-chunk quad*8 (8 bf16 = one 16B load)
  const u16* Br[4];
#pragma unroll
  for (int j = 0; j < 4; j++)
    Br[j] = Bt + (size_t)(n0 + cw + j * 16 + qm) * K + quad * 8;

  f32x4 acc[2][4] = {};
#pragma unroll 2
  for (int kt = 0; kt < K; kt += 32) {
    const float4 a00 = *(const float4*)(Ar0 + kt);
    const float4 a01 = *(const float4*)(Ar0 + kt + 4);
    const float4 a10 = *(const float4*)(Ar1 + kt);
    const float4 a11 = *(const float4*)(Ar1 + kt + 4);
    short8 bfr[4];
#pragma unroll
    for (int j = 0; j < 4; j++)
      bfr[j] = *(const short8*)(Br[j] + kt);
    u32 w0[4] = {pkbf(a00.x, a00.y), pkbf(a00.z, a00.w), pkbf(a01.x, a01.y), pkbf(a01.z, a01.w)};
    u32 w1[4] = {pkbf(a10.x, a10.y), pkbf(a10.z, a10.w), pkbf(a11.x, a11.y), pkbf(a11.z, a11.w)};
    short8 af[2] = {*(short8*)w0, *(short8*)w1};
#pragma unroll
    for (int i = 0; i < 2; i++)
#pragma unroll
      for (int j = 0; j < 4; j++)
        acc[i][j] = __builtin_amdgcn_mfma_f32_16x16x32_bf16(af[i], bfr[j], acc[i][j], 0, 0, 0);
  }
#pragma unroll
  for (int i = 0; i < 2; i++) {
    const int row = m0 + rw + i * 16 + quad * 4;   // D: row = quad*4 + reg
#pragma unroll
    for (int j = 0; j < 4; j++) {
      const int col = n0 + cw + j * 16 + qm;       // D: col = lane&15
#pragma unroll
      for (int r = 0; r < 4; r++)
        C[(size_t)(row + r) * 256 + col] = acc[i][j][r];
    }
  }
}

// ---------- MLP GEMM, LDS-free, fused bias+GELU+W2 dot -> atomic logits ----------
__global__ __launch_bounds__(256) void gemm_gelu_w2(const u16* __restrict__ Axb,
                                                    const u16* __restrict__ Bt,
                                                    const float* __restrict__ b1,
                                                    const float* __restrict__ W2,
                                                    float* __restrict__ logits) {
  constexpr int K = 768;
  const int tid = threadIdx.x;
  const int n0 = blockIdx.x * 128;
  const int m0 = blockIdx.y * 64;
  const int wave = tid >> 6, lane = tid & 63, qm = lane & 15, quad = lane >> 4;
  const int rw = (wave >> 1) * 32, cw = (wave & 1) * 64;

  const u16* Ar0 = Axb + (size_t)(m0 + rw + qm) * K + quad * 8;
  const u16* Ar1 = Ar0 + (size_t)16 * K;
  const u16* Br[4];
#pragma unroll
  for (int j = 0; j < 4; j++)
    Br[j] = Bt + (size_t)(n0 + cw + j * 16 + qm) * K + quad * 8;

  f32x4 acc[2][4] = {};
#pragma unroll 2
  for (int kt = 0; kt < K; kt += 32) {
    short8 af[2];
    af[0] = *(const short8*)(Ar0 + kt);
    af[1] = *(const short8*)(Ar1 + kt);
    short8 bfr[4];
#pragma unroll
    for (int j = 0; j < 4; j++)
      bfr[j] = *(const short8*)(Br[j] + kt);
#pragma unroll
    for (int i = 0; i < 2; i++)
#pragma unroll
      for (int j = 0; j < 4; j++)
        acc[i][j] = __builtin_amdgcn_mfma_f32_16x16x32_bf16(af[i], bfr[j], acc[i][j], 0, 0, 0);
  }

  // epilogue: partial logit = sum_j gelu(acc+b1)*W2; reduce over qm lanes; 1 atomic/row
  float w2j[4], bc[4];
#pragma unroll
  for (int j = 0; j < 4; j++) {
    const int col = n0 + cw + j * 16 + qm;
    w2j[j] = W2[col];
    bc[j] = b1[col];
  }
#pragma unroll
  for (int i = 0; i < 2; i++) {
#pragma unroll
    for (int r = 0; r < 4; r++) {
      float p = 0.0f;
#pragma unroll
      for (int j = 0; j < 4; j++)
        p += gelu_f(acc[i][j][r] + bc[j]) * w2j[j];
      p += __shfl_xor(p, 1);
      p += __shfl_xor(p, 2);
      p += __shfl_xor(p, 4);
      p += __shfl_xor(p, 8);
      if (qm == 0)
        atomicAdd(&logits[m0 + rw + i * 16 + quad * 4 + r], p);
    }
  }
}

// ---------- layernorm (bias added first) over both v and a ----------
__global__ __launch_bounds__(256) void ln2(float* __restrict__ v, float* __restrict__ a,
                                           const float* __restrict__ bv,
                                           const float* __restrict__ ba) {
  const int gr = blockIdx.x * 4 + (threadIdx.x >> 6);
  const int lane = threadIdx.x & 63;
  float* X; const float* bias; int row;
  if (gr < BT_ROWS) { X = v; bias = bv; row = gr; }
  else              { X = a; bias = ba; row = gr - BT_ROWS; }
  float4 x = *(float4*)&X[(size_t)row * 256 + lane * 4];
  const float4 b = *(const float4*)&bias[lane * 4];
  x.x += b.x; x.y += b.y; x.z += b.z; x.w += b.w;
  float s = x.x + x.y + x.z + x.w;
  float s2 = x.x * x.x + x.y * x.y + x.z * x.z + x.w * x.w;
  s = wave_bcast_sum(s);
  s2 = wave_bcast_sum(s2);
  const float mu = s * (1.0f / 256.0f);
  const float var = s2 * (1.0f / 256.0f) - mu * mu;
  const float inv = rsqrtf(var + 1e-5f);
  x.x = (x.x - mu) * inv; x.y = (x.y - mu) * inv;
  x.z = (x.z - mu) * inv; x.w = (x.w - mu) * inv;
  *(float4*)&X[(size_t)row * 256 + lane * 4] = x;
}

// ---------- fused: fractional shift + window avg + l2norm(actx,v) + concat ----------
__global__ __launch_bounds__(256) void shift_norm(const float* __restrict__ a,
                                                  const float* __restrict__ v,
                                                  float* __restrict__ actx,
                                                  u16* __restrict__ xb,
                                                  const float* __restrict__ theta) {
  const int row = blockIdx.x * 4 + (threadIdx.x >> 6);
  const int lane = threadIdx.x & 63;
  const int d4 = lane * 4;
  const int bb = row >> 11;
  const int t = row & (T_SEQ - 1);
  const float th = fminf(fmaxf(theta[0], -12.0f), 12.0f);
  const float delta = 2.0f + 4.0f * (1.0f / (1.0f + expf(-th)));
  const float dl = fminf(fmaxf(delta, 0.0f), (float)(T_SEQ - 1));
  const float nf = floorf(dl);
  const float alpha = dl - nf;
  const int ni = (int)nf;
  const float center = fminf(fmaxf((float)t + delta, 0.0f), (float)t);
  float sx = 0, sy = 0, sz = 0, sw = 0, cnt = 0.0f;
  const float* ab = a + (size_t)bb * T_SEQ * 256;
#pragma unroll
  for (int j = 0; j < 6; j++) {
    const int tau = t - 5 + j;
    if (tau < 0) continue;
    if (fabsf((float)tau - center) > 5.0f) continue;
    cnt += 1.0f;
    const int i0 = min(max(tau - ni, 0), T_SEQ - 1);
    const int i1 = min(i0 + 1, T_SEQ - 1);
    const float4 a0 = *(const float4*)&ab[(size_t)i0 * 256 + d4];
    const float4 a1 = *(const float4*)&ab[(size_t)i1 * 256 + d4];
    sx += a0.x + alpha * (a1.x - a0.x);
    sy += a0.y + alpha * (a1.y - a0.y);
    sz += a0.z + alpha * (a1.z - a0.z);
    sw += a0.w + alpha * (a1.w - a0.w);
  }
  const float sc = 1.0f / fmaxf(cnt, 1e-8f);
  float4 o; o.x = sx * sc; o.y = sy * sc; o.z = sz * sc; o.w = sw * sc;
  *(float4*)&actx[(size_t)row * 256 + d4] = o;
  const float4 vv = *(const float4*)&v[(size_t)row * 256 + d4];
  float sa2 = o.x * o.x + o.y * o.y + o.z * o.z + o.w * o.w;
  float sv2 = vv.x * vv.x + vv.y * vv.y + vv.z * vv.z + vv.w * vv.w;
  sa2 = wave_bcast_sum(sa2);
  sv2 = wave_bcast_sum(sv2);
  const float ia = 1.0f / fmaxf(sqrtf(sa2), 1e-8f);
  const float iv = 1.0f / fmaxf(sqrtf(sv2), 1e-8f);
  const float anx = o.x * ia, any_ = o.y * ia, anz = o.z * ia, anw = o.w * ia;
  const float vnx = vv.x * iv, vny = vv.y * iv, vnz = vv.z * iv, vnw = vv.w * iv;
  u16* xr = xb + (size_t)row * 768;
  u32 pa[2] = {pkbf(anx, any_), pkbf(anz, anw)};
  u32 pv[2] = {pkbf(vnx, vny), pkbf(vnz, vnw)};
  u32 pp[2] = {pkbf(anx * vnx, any_ * vny), pkbf(anz * vnz, anw * vnw)};
  *(uint2*)&xr[d4] = *(uint2*)pa;
  *(uint2*)&xr[256 + d4] = *(uint2*)pv;
  *(uint2*)&xr[512 + d4] = *(uint2*)pp;
}

// ---------- gate + mix ----------
__global__ __launch_bounds__(256) void gate_mix(const float* __restrict__ logits,
                                                const float* __restrict__ b2,
                                                const float* __restrict__ actx,
                                                const float* __restrict__ v,
                                                float* __restrict__ out) {
  const int row = blockIdx.x * 4 + (threadIdx.x >> 6);
  const int lane = threadIdx.x & 63;
  const float l = fminf(fmaxf(logits[row] + b2[0], -12.0f), 12.0f);
  float g = 1.0f / (1.0f + expf(-l));
  g = fminf(fmaxf(g, 0.05f), 0.95f);
  const float4 aa = *(const float4*)&actx[(size_t)row * 256 + lane * 4];
  const float4 vv = *(const float4*)&v[(size_t)row * 256 + lane * 4];
  float4 o;
  o.x = g * aa.x + (1.0f - g) * vv.x;
  o.y = g * aa.y + (1.0f - g) * vv.y;
  o.z = g * aa.z + (1.0f - g) * vv.z;
  o.w = g * aa.w + (1.0f - g) * vv.w;
  *(float4*)&out[(size_t)row * 256 + lane * 4] = o;
}

// ---------- launch ----------
extern "C" void kernel_launch(void* const* d_in, const int* in_sizes, int n_in,
                              void* d_out, int out_size, void* d_ws, size_t ws_size,
                              hipStream_t stream) {
  const float* video = (const float*)d_in[0];
  const float* audio = (const float*)d_in[1];
  const float* Wv    = (const float*)d_in[2];
  const float* bv    = (const float*)d_in[3];
  const float* Wa    = (const float*)d_in[4];
  const float* ba    = (const float*)d_in[5];
  const float* theta = (const float*)d_in[6];
  const float* W1    = (const float*)d_in[7];
  const float* b1    = (const float*)d_in[8];
  const float* W2    = (const float*)d_in[9];
  const float* b2    = (const float*)d_in[10];
  float* out = (float*)d_out;
  char* ws = (char*)d_ws;

  const size_t OFF_WVT = 0;          // [256][1024] bf16
  const size_t OFF_WAT = 524288;     // [256][768]  bf16
  const size_t OFF_W1T = 917504;     // [1024][768] bf16
  const size_t OFF_LOG = 2490368;    // [16384] f32
  const size_t OFF_V   = 2555904;    // [16384][256] f32
  const size_t OFF_A   = 19333120;   // [16384][256] f32
  const size_t OFF_ACTX= 36110336;   // [16384][256] f32
  const size_t OFF_XB  = 52887552;   // [16384][768] bf16

  u16* wvT = (u16*)(ws + OFF_WVT);
  u16* waT = (u16*)(ws + OFF_WAT);
  u16* w1T = (u16*)(ws + OFF_W1T);
  float* logits = (float*)(ws + OFF_LOG);
  float* v    = (float*)(ws + OFF_V);
  float* a    = (float*)(ws + OFF_A);
  float* actx = (float*)(ws + OFF_ACTX);
  u16* xb = (u16*)(ws + OFF_XB);

  tcvt_all<<<1280, 256, 0, stream>>>(Wv, Wa, W1, wvT, waT, w1T, logits);
  gemm_proj<<<1024, 256, 0, stream>>>(video, audio, wvT, waT, v, a);
  ln2<<<2 * BT_ROWS / 4, 256, 0, stream>>>(v, a, bv, ba);
  shift_norm<<<BT_ROWS / 4, 256, 0, stream>>>(a, v, actx, xb, theta);
  gemm_gelu_w2<<<dim3(8, BT_ROWS / 64), 256, 0, stream>>>(xb, w1T, b1, W2, logits);
  gate_mix<<<BT_ROWS / 4, 256, 0, stream>>>(logits, b2, actx, v, out);
}

// Round 7
// 302.646 us; speedup vs baseline: 2.0688x; 1.3680x over previous
//
#include <hip/hip_runtime.h>
#include <cstdint>
#include <cstddef>

typedef unsigned short u16;
typedef unsigned int u32;
typedef __attribute__((ext_vector_type(8))) short short8;
typedef __attribute__((ext_vector_type(4))) float f32x4;

#define T_SEQ 2048
#define BT_ROWS 16384

// ---------- helpers ----------
__device__ __forceinline__ u16 f2bf(float x) {
  union { float f; u32 u; } v; v.f = x;
  u32 r = v.u + 0x7fffu + ((v.u >> 16) & 1u);
  return (u16)(r >> 16);
}
// pack two floats -> two bf16 in one u32 (lo in low half)
__device__ __forceinline__ u32 pkbf(float lo, float hi) {
  union { float f; u32 u; } a, b; a.f = lo; b.f = hi;
  const u32 ra = a.u + 0x7fffu + ((a.u >> 16) & 1u);
  const u32 rb = b.u + 0x7fffu + ((b.u >> 16) & 1u);
  return __builtin_amdgcn_perm(rb, ra, 0x07060302);
}
__device__ __forceinline__ float wave_bcast_sum(float x) {
#pragma unroll
  for (int off = 32; off > 0; off >>= 1) x += __shfl_down(x, off);
  return __shfl(x, 0);
}
__device__ __forceinline__ void gl_lds16(const void* g, void* l) {
  __builtin_amdgcn_global_load_lds((const __attribute__((address_space(1))) u32*)g,
                                   (__attribute__((address_space(3))) u32*)l, 16, 0, 0);
}
// tanh-form GELU; |diff| vs erf ~3e-4
__device__ __forceinline__ float gelu_f(float x) {
  float z = 1.5957691216057308f * x * (1.0f + 0.044715f * x * x);
  float e = __expf(z);
  return x - x * __builtin_amdgcn_rcpf(1.0f + e);
}

// ---------- transpose+convert all 3 weights + zero logits ----------
__global__ __launch_bounds__(256) void tcvt_all(const float* __restrict__ Wv,
                                                const float* __restrict__ Wa,
                                                const float* __restrict__ W1,
                                                u16* __restrict__ wvT,
                                                u16* __restrict__ waT,
                                                u16* __restrict__ w1T,
                                                float* __restrict__ logits) {
  int b = blockIdx.x;
  if (b >= 1216) {  // 64 blocks zero the 16384-float logits buffer
    logits[(b - 1216) * 256 + threadIdx.x] = 0.0f;
    return;
  }
  __shared__ float tile[32][33];
  const float* in; u16* out; int K, N, bx, by;
  if (b < 256)      { in = Wv; out = wvT; K = 1024; N = 256;  bx = b & 31;  by = b >> 5; }
  else if (b < 448) { b -= 256; in = Wa; out = waT; K = 768; N = 256;  bx = b % 24; by = b / 24; }
  else              { b -= 448; in = W1; out = w1T; K = 768; N = 1024; bx = b % 24; by = b / 24; }
  const int k0 = bx * 32, n0 = by * 32;
  const int tx = threadIdx.x & 31, ty = threadIdx.x >> 5;
#pragma unroll
  for (int r = 0; r < 4; r++)
    tile[ty + r * 8][tx] = in[(size_t)(k0 + ty + r * 8) * N + n0 + tx];
  __syncthreads();
#pragma unroll
  for (int r = 0; r < 4; r++)
    out[(size_t)(n0 + ty + r * 8) * K + k0 + tx] = f2bf(tile[tx][ty + r * 8]);
}

// ---------- merged projection GEMM: 64x64 tile, BK=32, 12KB LDS, 2048 blocks ----------
// C[M][256] f32 = A[M][K] f32 @ Bt[256][K] bf16^T.
// Blocks 0..1023: video (K=1024); 1024..2047: audio (K=768).
__global__ __launch_bounds__(256, 6) void gemm_proj(const float* __restrict__ Vin,
                                                    const float* __restrict__ Ain,
                                                    const u16* __restrict__ wvT,
                                                    const u16* __restrict__ waT,
                                                    float* __restrict__ Cv,
                                                    float* __restrict__ Ca) {
  __shared__ float Asf[64 * 32];   // 8 KB
  __shared__ u16 Bs[64 * 32];      // 4 KB
  int b = blockIdx.x;
  const float* A; const u16* Bt; float* C; int K;
  if (b < 1024) { A = Vin; Bt = wvT; C = Cv; K = 1024; }
  else          { b -= 1024; A = Ain; Bt = waT; C = Ca; K = 768; }
  const int m0 = (b >> 2) * 64;
  const int n0 = (b & 3) * 64;
  const int tid = threadIdx.x;
  const int wave = tid >> 6, lane = tid & 63, qm = lane & 15, quad = lane >> 4;
  const int rw = (wave >> 1) * 32, cw = (wave & 1) * 32;

  // A staging: 64 rows x 8 16B-parts; chunk c -> row c>>3, global part (c&7)^(row&7)
  const int arow = tid >> 3;
  const int apart = (tid & 7) ^ (arow & 7);
  const float* Ap0 = A + (size_t)(m0 + arow) * K + apart * 4;
  const float* Ap1 = A + (size_t)(m0 + arow + 32) * K + apart * 4;
  // B staging: 64 rows x 4 16B-parts; chunk c -> row c>>2, global part (c&3)^(row&3)
  const int brow = tid >> 2;
  const int bpart = (tid & 3) ^ (brow & 3);
  const u16* Bp = Bt + (size_t)(n0 + brow) * K + bpart * 8;

  f32x4 acc[2][2] = {};
  for (int kt = 0; kt < K; kt += 32) {
    gl_lds16(Ap0 + kt, &Asf[tid * 4]);
    gl_lds16(Ap1 + kt, &Asf[(tid + 256) * 4]);
    gl_lds16(Bp + kt, &Bs[tid * 8]);
    __syncthreads();
    short8 af[2], bfr[2];
#pragma unroll
    for (int i = 0; i < 2; i++) {
      const int r = rw + i * 16 + qm;
      const float4 f0 = *(const float4*)&Asf[(r * 8 + ((quad * 2) ^ (r & 7))) * 4];
      const float4 f1 = *(const float4*)&Asf[(r * 8 + ((quad * 2 + 1) ^ (r & 7))) * 4];
      u32 w[4] = {pkbf(f0.x, f0.y), pkbf(f0.z, f0.w), pkbf(f1.x, f1.y), pkbf(f1.z, f1.w)};
      af[i] = *(short8*)w;
    }
#pragma unroll
    for (int j = 0; j < 2; j++) {
      const int r = cw + j * 16 + qm;
      bfr[j] = *(const short8*)&Bs[(r * 4 + (quad ^ (r & 3))) * 8];
    }
#pragma unroll
    for (int i = 0; i < 2; i++)
#pragma unroll
      for (int j = 0; j < 2; j++)
        acc[i][j] = __builtin_amdgcn_mfma_f32_16x16x32_bf16(af[i], bfr[j], acc[i][j], 0, 0, 0);
    __syncthreads();
  }
#pragma unroll
  for (int i = 0; i < 2; i++) {
    const int row = m0 + rw + i * 16 + quad * 4;   // D: row = quad*4 + reg
#pragma unroll
    for (int j = 0; j < 2; j++) {
      const int col = n0 + cw + j * 16 + qm;       // D: col = lane&15
#pragma unroll
      for (int r = 0; r < 4; r++)
        C[(size_t)(row + r) * 256 + col] = acc[i][j][r];
    }
  }
}

// ---------- MLP GEMM: 64x128 tile, BK=32, 12KB LDS, 2048 blocks ----------
// fused bias+GELU+W2 partial dot -> atomic logits (no H tensor)
__global__ __launch_bounds__(256, 6) void gemm_gelu_w2(const u16* __restrict__ Axb,
                                                       const u16* __restrict__ Bt,
                                                       const float* __restrict__ b1,
                                                       const float* __restrict__ W2,
                                                       float* __restrict__ logits) {
  constexpr int K = 768;
  __shared__ u16 As[64 * 32];    // 4 KB
  __shared__ u16 Bs[128 * 32];   // 8 KB
  const int tid = threadIdx.x;
  const int n0 = blockIdx.x * 128;   // x = n: consecutive blocks share A m-tile
  const int m0 = blockIdx.y * 64;
  const int wave = tid >> 6, lane = tid & 63, qm = lane & 15, quad = lane >> 4;
  const int rw = (wave >> 1) * 32, cw = (wave & 1) * 64;

  // A: 64 rows x 4 parts (1 chunk/thread); B: 128 rows x 4 parts (2 chunks/thread)
  const int crow = tid >> 2;
  const int cpart = (tid & 3) ^ (crow & 3);
  const u16* Ap = Axb + (size_t)(m0 + crow) * K + cpart * 8;
  const u16* Bp0 = Bt + (size_t)(n0 + crow) * K + cpart * 8;
  const u16* Bp1 = Bt + (size_t)(n0 + crow + 64) * K + cpart * 8;

  f32x4 acc[2][4] = {};
  for (int kt = 0; kt < K; kt += 32) {
    gl_lds16(Ap + kt, &As[tid * 8]);
    gl_lds16(Bp0 + kt, &Bs[tid * 8]);
    gl_lds16(Bp1 + kt, &Bs[(tid + 256) * 8]);
    __syncthreads();
    short8 af[2], bfr[4];
#pragma unroll
    for (int i = 0; i < 2; i++) {
      const int r = rw + i * 16 + qm;
      af[i] = *(const short8*)&As[(r * 4 + (quad ^ (r & 3))) * 8];
    }
#pragma unroll
    for (int j = 0; j < 4; j++) {
      const int r = cw + j * 16 + qm;
      bfr[j] = *(const short8*)&Bs[(r * 4 + (quad ^ (r & 3))) * 8];
    }
#pragma unroll
    for (int i = 0; i < 2; i++)
#pragma unroll
      for (int j = 0; j < 4; j++)
        acc[i][j] = __builtin_amdgcn_mfma_f32_16x16x32_bf16(af[i], bfr[j], acc[i][j], 0, 0, 0);
    __syncthreads();
  }

  // epilogue: partial logit = sum_j gelu(acc+b1)*W2; reduce over qm lanes; 1 atomic/row
  float w2j[4], bc[4];
#pragma unroll
  for (int j = 0; j < 4; j++) {
    const int col = n0 + cw + j * 16 + qm;
    w2j[j] = W2[col];
    bc[j] = b1[col];
  }
#pragma unroll
  for (int i = 0; i < 2; i++) {
#pragma unroll
    for (int r = 0; r < 4; r++) {
      float p = 0.0f;
#pragma unroll
      for (int j = 0; j < 4; j++)
        p += gelu_f(acc[i][j][r] + bc[j]) * w2j[j];
      p += __shfl_xor(p, 1);
      p += __shfl_xor(p, 2);
      p += __shfl_xor(p, 4);
      p += __shfl_xor(p, 8);
      if (qm == 0)
        atomicAdd(&logits[m0 + rw + i * 16 + quad * 4 + r], p);
    }
  }
}

// ---------- layernorm (bias added first) over both v and a ----------
__global__ __launch_bounds__(256) void ln2(float* __restrict__ v, float* __restrict__ a,
                                           const float* __restrict__ bv,
                                           const float* __restrict__ ba) {
  const int gr = blockIdx.x * 4 + (threadIdx.x >> 6);
  const int lane = threadIdx.x & 63;
  float* X; const float* bias; int row;
  if (gr < BT_ROWS) { X = v; bias = bv; row = gr; }
  else              { X = a; bias = ba; row = gr - BT_ROWS; }
  float4 x = *(float4*)&X[(size_t)row * 256 + lane * 4];
  const float4 b = *(const float4*)&bias[lane * 4];
  x.x += b.x; x.y += b.y; x.z += b.z; x.w += b.w;
  float s = x.x + x.y + x.z + x.w;
  float s2 = x.x * x.x + x.y * x.y + x.z * x.z + x.w * x.w;
  s = wave_bcast_sum(s);
  s2 = wave_bcast_sum(s2);
  const float mu = s * (1.0f / 256.0f);
  const float var = s2 * (1.0f / 256.0f) - mu * mu;
  const float inv = rsqrtf(var + 1e-5f);
  x.x = (x.x - mu) * inv; x.y = (x.y - mu) * inv;
  x.z = (x.z - mu) * inv; x.w = (x.w - mu) * inv;
  *(float4*)&X[(size_t)row * 256 + lane * 4] = x;
}

// ---------- fused: fractional shift + window avg + l2norm(actx,v) + concat ----------
__global__ __launch_bounds__(256) void shift_norm(const float* __restrict__ a,
                                                  const float* __restrict__ v,
                                                  float* __restrict__ actx,
                                                  u16* __restrict__ xb,
                                                  const float* __restrict__ theta) {
  const int row = blockIdx.x * 4 + (threadIdx.x >> 6);
  const int lane = threadIdx.x & 63;
  const int d4 = lane * 4;
  const int bb = row >> 11;
  const int t = row & (T_SEQ - 1);
  const float th = fminf(fmaxf(theta[0], -12.0f), 12.0f);
  const float delta = 2.0f + 4.0f * (1.0f / (1.0f + expf(-th)));
  const float dl = fminf(fmaxf(delta, 0.0f), (float)(T_SEQ - 1));
  const float nf = floorf(dl);
  const float alpha = dl - nf;
  const int ni = (int)nf;
  const float center = fminf(fmaxf((float)t + delta, 0.0f), (float)t);
  float sx = 0, sy = 0, sz = 0, sw = 0, cnt = 0.0f;
  const float* ab = a + (size_t)bb * T_SEQ * 256;
#pragma unroll
  for (int j = 0; j < 6; j++) {
    const int tau = t - 5 + j;
    if (tau < 0) continue;
    if (fabsf((float)tau - center) > 5.0f) continue;
    cnt += 1.0f;
    const int i0 = min(max(tau - ni, 0), T_SEQ - 1);
    const int i1 = min(i0 + 1, T_SEQ - 1);
    const float4 a0 = *(const float4*)&ab[(size_t)i0 * 256 + d4];
    const float4 a1 = *(const float4*)&ab[(size_t)i1 * 256 + d4];
    sx += a0.x + alpha * (a1.x - a0.x);
    sy += a0.y + alpha * (a1.y - a0.y);
    sz += a0.z + alpha * (a1.z - a0.z);
    sw += a0.w + alpha * (a1.w - a0.w);
  }
  const float sc = 1.0f / fmaxf(cnt, 1e-8f);
  float4 o; o.x = sx * sc; o.y = sy * sc; o.z = sz * sc; o.w = sw * sc;
  *(float4*)&actx[(size_t)row * 256 + d4] = o;
  const float4 vv = *(const float4*)&v[(size_t)row * 256 + d4];
  float sa2 = o.x * o.x + o.y * o.y + o.z * o.z + o.w * o.w;
  float sv2 = vv.x * vv.x + vv.y * vv.y + vv.z * vv.z + vv.w * vv.w;
  sa2 = wave_bcast_sum(sa2);
  sv2 = wave_bcast_sum(sv2);
  const float ia = 1.0f / fmaxf(sqrtf(sa2), 1e-8f);
  const float iv = 1.0f / fmaxf(sqrtf(sv2), 1e-8f);
  const float anx = o.x * ia, any_ = o.y * ia, anz = o.z * ia, anw = o.w * ia;
  const float vnx = vv.x * iv, vny = vv.y * iv, vnz = vv.z * iv, vnw = vv.w * iv;
  u16* xr = xb + (size_t)row * 768;
  u32 pa[2] = {pkbf(anx, any_), pkbf(anz, anw)};
  u32 pv[2] = {pkbf(vnx, vny), pkbf(vnz, vnw)};
  u32 pp[2] = {pkbf(anx * vnx, any_ * vny), pkbf(anz * vnz, anw * vnw)};
  *(uint2*)&xr[d4] = *(uint2*)pa;
  *(uint2*)&xr[256 + d4] = *(uint2*)pv;
  *(uint2*)&xr[512 + d4] = *(uint2*)pp;
}

// ---------- gate + mix ----------
__global__ __launch_bounds__(256) void gate_mix(const float* __restrict__ logits,
                                                const float* __restrict__ b2,
                                                const float* __restrict__ actx,
                                                const float* __restrict__ v,
                                                float* __restrict__ out) {
  const int row = blockIdx.x * 4 + (threadIdx.x >> 6);
  const int lane = threadIdx.x & 63;
  const float l = fminf(fmaxf(logits[row] + b2[0], -12.0f), 12.0f);
  float g = 1.0f / (1.0f + expf(-l));
  g = fminf(fmaxf(g, 0.05f), 0.95f);
  const float4 aa = *(const float4*)&actx[(size_t)row * 256 + lane * 4];
  const float4 vv = *(const float4*)&v[(size_t)row * 256 + lane * 4];
  float4 o;
  o.x = g * aa.x + (1.0f - g) * vv.x;
  o.y = g * aa.y + (1.0f - g) * vv.y;
  o.z = g * aa.z + (1.0f - g) * vv.z;
  o.w = g * aa.w + (1.0f - g) * vv.w;
  *(float4*)&out[(size_t)row * 256 + lane * 4] = o;
}

// ---------- launch ----------
extern "C" void kernel_launch(void* const* d_in, const int* in_sizes, int n_in,
                              void* d_out, int out_size, void* d_ws, size_t ws_size,
                              hipStream_t stream) {
  const float* video = (const float*)d_in[0];
  const float* audio = (const float*)d_in[1];
  const float* Wv    = (const float*)d_in[2];
  const float* bv    = (const float*)d_in[3];
  const float* Wa    = (const float*)d_in[4];
  const float* ba    = (const float*)d_in[5];
  const float* theta = (const float*)d_in[6];
  const float* W1    = (const float*)d_in[7];
  const float* b1    = (const float*)d_in[8];
  const float* W2    = (const float*)d_in[9];
  const float* b2    = (const float*)d_in[10];
  float* out = (float*)d_out;
  char* ws = (char*)d_ws;

  const size_t OFF_WVT = 0;          // [256][1024] bf16
  const size_t OFF_WAT = 524288;     // [256][768]  bf16
  const size_t OFF_W1T = 917504;     // [1024][768] bf16
  const size_t OFF_LOG = 2490368;    // [16384] f32
  const size_t OFF_V   = 2555904;    // [16384][256] f32
  const size_t OFF_A   = 19333120;   // [16384][256] f32
  const size_t OFF_ACTX= 36110336;   // [16384][256] f32
  const size_t OFF_XB  = 52887552;   // [16384][768] bf16

  u16* wvT = (u16*)(ws + OFF_WVT);
  u16* waT = (u16*)(ws + OFF_WAT);
  u16* w1T = (u16*)(ws + OFF_W1T);
  float* logits = (float*)(ws + OFF_LOG);
  float* v    = (float*)(ws + OFF_V);
  float* a    = (float*)(ws + OFF_A);
  float* actx = (float*)(ws + OFF_ACTX);
  u16* xb = (u16*)(ws + OFF_XB);

  tcvt_all<<<1280, 256, 0, stream>>>(Wv, Wa, W1, wvT, waT, w1T, logits);
  gemm_proj<<<2048, 256, 0, stream>>>(video, audio, wvT, waT, v, a);
  ln2<<<2 * BT_ROWS / 4, 256, 0, stream>>>(v, a, bv, ba);
  shift_norm<<<BT_ROWS / 4, 256, 0, stream>>>(a, v, actx, xb, theta);
  gemm_gelu_w2<<<dim3(8, BT_ROWS / 64), 256, 0, stream>>>(xb, w1T, b1, W2, logits);
  gate_mix<<<BT_ROWS / 4, 256, 0, stream>>>(logits, b2, actx, v, out);
}

// Round 8
// 260.693 us; speedup vs baseline: 2.4017x; 1.1609x over previous
//
#include <hip/hip_runtime.h>
#include <cstdint>
#include <cstddef>

typedef unsigned short u16;
typedef unsigned int u32;
typedef __attribute__((ext_vector_type(8))) short short8;
typedef __attribute__((ext_vector_type(4))) float f32x4;

#define T_SEQ 2048
#define BT_ROWS 16384

// ---------- helpers ----------
__device__ __forceinline__ u16 f2bf(float x) {
  union { float f; u32 u; } v; v.f = x;
  u32 r = v.u + 0x7fffu + ((v.u >> 16) & 1u);
  return (u16)(r >> 16);
}
// pack two floats -> two bf16 in one u32 (lo in low half)
__device__ __forceinline__ u32 pkbf(float lo, float hi) {
  union { float f; u32 u; } a, b; a.f = lo; b.f = hi;
  const u32 ra = a.u + 0x7fffu + ((a.u >> 16) & 1u);
  const u32 rb = b.u + 0x7fffu + ((b.u >> 16) & 1u);
  return __builtin_amdgcn_perm(rb, ra, 0x07060302);
}
__device__ __forceinline__ float wave_bcast_sum(float x) {
#pragma unroll
  for (int off = 32; off > 0; off >>= 1) x += __shfl_down(x, off);
  return __shfl(x, 0);
}
__device__ __forceinline__ void gl_lds16(const void* g, void* l) {
  __builtin_amdgcn_global_load_lds((const __attribute__((address_space(1))) u32*)g,
                                   (__attribute__((address_space(3))) u32*)l, 16, 0, 0);
}
// tanh-form GELU; |diff| vs erf ~3e-4
__device__ __forceinline__ float gelu_f(float x) {
  float z = 1.5957691216057308f * x * (1.0f + 0.044715f * x * x);
  float e = __expf(z);
  return x - x * __builtin_amdgcn_rcpf(1.0f + e);
}

// ---------- transpose+convert all 3 weights + zero logits ----------
__global__ __launch_bounds__(256) void tcvt_all(const float* __restrict__ Wv,
                                                const float* __restrict__ Wa,
                                                const float* __restrict__ W1,
                                                u16* __restrict__ wvT,
                                                u16* __restrict__ waT,
                                                u16* __restrict__ w1T,
                                                float* __restrict__ logits) {
  int b = blockIdx.x;
  if (b >= 1216) {  // 64 blocks zero the 16384-float logits buffer
    logits[(b - 1216) * 256 + threadIdx.x] = 0.0f;
    return;
  }
  __shared__ float tile[32][33];
  const float* in; u16* out; int K, N, bx, by;
  if (b < 256)      { in = Wv; out = wvT; K = 1024; N = 256;  bx = b & 31;  by = b >> 5; }
  else if (b < 448) { b -= 256; in = Wa; out = waT; K = 768; N = 256;  bx = b % 24; by = b / 24; }
  else              { b -= 448; in = W1; out = w1T; K = 768; N = 1024; bx = b % 24; by = b / 24; }
  const int k0 = bx * 32, n0 = by * 32;
  const int tx = threadIdx.x & 31, ty = threadIdx.x >> 5;
#pragma unroll
  for (int r = 0; r < 4; r++)
    tile[ty + r * 8][tx] = in[(size_t)(k0 + ty + r * 8) * N + n0 + tx];
  __syncthreads();
#pragma unroll
  for (int r = 0; r < 4; r++)
    out[(size_t)(n0 + ty + r * 8) * K + k0 + tx] = f2bf(tile[tx][ty + r * 8]);
}

// ---------- merged projection GEMM, split-K=2, tile 64x128, BK=64 (r4 layout) ----------
// Partial C halves go to separate buffers (C0/C1), summed in ln2. A traffic stays 1x
// (k-halves disjoint), grid doubles to 2048 -> 5 blocks/CU (LDS 32 KB).
// Blocks 0..1023: video (K=1024); 1024..2047: audio (K=768).
__global__ __launch_bounds__(256, 5) void gemm_proj(const float* __restrict__ Vin,
                                                    const float* __restrict__ Ain,
                                                    const u16* __restrict__ wvT,
                                                    const u16* __restrict__ waT,
                                                    float* __restrict__ Cv0,
                                                    float* __restrict__ Cv1,
                                                    float* __restrict__ Ca0,
                                                    float* __restrict__ Ca1) {
  __shared__ float Asf[64 * 64];   // 16 KB
  __shared__ u16 Bs[128 * 64];     // 16 KB
  int b = blockIdx.x;
  const float* A; const u16* Bt; float* C0; float* C1; int K;
  if (b < 1024) { A = Vin; Bt = wvT; C0 = Cv0; C1 = Cv1; K = 1024; }
  else          { b -= 1024; A = Ain; Bt = waT; C0 = Ca0; C1 = Ca1; K = 768; }
  const int kh = b & 1;
  const int n0 = ((b >> 1) & 1) * 128;
  const int m0 = (b >> 2) * 64;
  const int K2 = K >> 1;
  float* C = kh ? C1 : C0;
  A += (size_t)kh * K2;   // column offset into this k-half
  Bt += (size_t)kh * K2;
  const int tid = threadIdx.x;
  const int wave = tid >> 6, lane = tid & 63, qm = lane & 15, quad = lane >> 4;
  const int rw = (wave >> 1) * 32, cw = (wave & 1) * 64;

  // r4-verified swizzled chunk layout (0 bank conflicts)
  const int arow = tid >> 4;
  const int apart = (tid & 15) ^ (arow & 15);
  const float* Ap[4];
#pragma unroll
  for (int g = 0; g < 4; g++)
    Ap[g] = A + (size_t)(m0 + arow + g * 16) * K + apart * 4;
  const int brow = tid >> 3;
  const int bpart = (tid & 7) ^ (brow & 7);
  const u16* Bp[4];
#pragma unroll
  for (int g = 0; g < 4; g++)
    Bp[g] = Bt + (size_t)(n0 + brow + g * 32) * K + bpart * 8;

  f32x4 acc[2][4] = {};
  for (int kt = 0; kt < K2; kt += 64) {
#pragma unroll
    for (int g = 0; g < 4; g++) gl_lds16(Ap[g] + kt, &Asf[(tid + g * 256) * 4]);
#pragma unroll
    for (int g = 0; g < 4; g++) gl_lds16(Bp[g] + kt, &Bs[(tid + g * 256) * 8]);
    __syncthreads();
#pragma unroll
    for (int s = 0; s < 2; s++) {
      short8 af[2], bfr[4];
#pragma unroll
      for (int i = 0; i < 2; i++) {
        const int r = rw + i * 16 + qm;
        const int pb = s * 8 + quad * 2;
        const float4 f0 = *(const float4*)&Asf[r * 64 + ((pb) ^ (r & 15)) * 4];
        const float4 f1 = *(const float4*)&Asf[r * 64 + ((pb + 1) ^ (r & 15)) * 4];
        u32 w[4] = {pkbf(f0.x, f0.y), pkbf(f0.z, f0.w), pkbf(f1.x, f1.y), pkbf(f1.z, f1.w)};
        af[i] = *(short8*)w;
      }
#pragma unroll
      for (int j = 0; j < 4; j++) {
        const int r = cw + j * 16 + qm;
        bfr[j] = *(const short8*)&Bs[r * 64 + ((s * 4 + quad) ^ (r & 7)) * 8];
      }
#pragma unroll
      for (int i = 0; i < 2; i++)
#pragma unroll
        for (int j = 0; j < 4; j++)
          acc[i][j] = __builtin_amdgcn_mfma_f32_16x16x32_bf16(af[i], bfr[j], acc[i][j], 0, 0, 0);
    }
    __syncthreads();
  }
#pragma unroll
  for (int i = 0; i < 2; i++) {
    const int row = m0 + rw + i * 16 + quad * 4;   // D: row = quad*4 + reg
#pragma unroll
    for (int j = 0; j < 4; j++) {
      const int col = n0 + cw + j * 16 + qm;       // D: col = lane&15
#pragma unroll
      for (int r = 0; r < 4; r++)
        C[(size_t)(row + r) * 256 + col] = acc[i][j][r];
    }
  }
}

// ---------- MLP GEMM (r4-proven): tile 64x128, BK=64, fused bias+GELU+W2 -> atomic logits ----------
__global__ __launch_bounds__(256, 6) void gemm_gelu_w2(const u16* __restrict__ Axb,
                                                       const u16* __restrict__ Bt,
                                                       const float* __restrict__ b1,
                                                       const float* __restrict__ W2,
                                                       float* __restrict__ logits) {
  constexpr int K = 768;
  __shared__ u16 As[64 * 64];    // 8 KB
  __shared__ u16 Bs[128 * 64];   // 16 KB
  const int tid = threadIdx.x;
  const int n0 = blockIdx.x * 128;   // x = n: consecutive blocks share A m-tile
  const int m0 = blockIdx.y * 64;
  const int wave = tid >> 6, lane = tid & 63, qm = lane & 15, quad = lane >> 4;
  const int rw = (wave >> 1) * 32, cw = (wave & 1) * 64;

  const int crow = tid >> 3;
  const int cpart = (tid & 7) ^ (crow & 7);
  const u16* Ap[2];
#pragma unroll
  for (int g = 0; g < 2; g++)
    Ap[g] = Axb + (size_t)(m0 + crow + g * 32) * K + cpart * 8;
  const u16* Bp[4];
#pragma unroll
  for (int g = 0; g < 4; g++)
    Bp[g] = Bt + (size_t)(n0 + crow + g * 32) * K + cpart * 8;

  f32x4 acc[2][4] = {};
  for (int kt = 0; kt < K; kt += 64) {
#pragma unroll
    for (int g = 0; g < 2; g++) gl_lds16(Ap[g] + kt, &As[(tid + g * 256) * 8]);
#pragma unroll
    for (int g = 0; g < 4; g++) gl_lds16(Bp[g] + kt, &Bs[(tid + g * 256) * 8]);
    __syncthreads();
#pragma unroll
    for (int s = 0; s < 2; s++) {
      short8 af[2], bfr[4];
#pragma unroll
      for (int i = 0; i < 2; i++) {
        const int r = rw + i * 16 + qm;
        af[i] = *(const short8*)&As[r * 64 + ((s * 4 + quad) ^ (r & 7)) * 8];
      }
#pragma unroll
      for (int j = 0; j < 4; j++) {
        const int r = cw + j * 16 + qm;
        bfr[j] = *(const short8*)&Bs[r * 64 + ((s * 4 + quad) ^ (r & 7)) * 8];
      }
#pragma unroll
      for (int i = 0; i < 2; i++)
#pragma unroll
        for (int j = 0; j < 4; j++)
          acc[i][j] = __builtin_amdgcn_mfma_f32_16x16x32_bf16(af[i], bfr[j], acc[i][j], 0, 0, 0);
    }
    __syncthreads();
  }

  float w2j[4], bc[4];
#pragma unroll
  for (int j = 0; j < 4; j++) {
    const int col = n0 + cw + j * 16 + qm;
    w2j[j] = W2[col];
    bc[j] = b1[col];
  }
#pragma unroll
  for (int i = 0; i < 2; i++) {
#pragma unroll
    for (int r = 0; r < 4; r++) {
      float p = 0.0f;
#pragma unroll
      for (int j = 0; j < 4; j++)
        p += gelu_f(acc[i][j][r] + bc[j]) * w2j[j];
      p += __shfl_xor(p, 1);
      p += __shfl_xor(p, 2);
      p += __shfl_xor(p, 4);
      p += __shfl_xor(p, 8);
      if (qm == 0)
        atomicAdd(&logits[m0 + rw + i * 16 + quad * 4 + r], p);
    }
  }
}

// ---------- layernorm over (C0+C1+bias), written in place into C0 ----------
__global__ __launch_bounds__(256) void ln2(float* __restrict__ v0, const float* __restrict__ v1,
                                           float* __restrict__ a0, const float* __restrict__ a1,
                                           const float* __restrict__ bv,
                                           const float* __restrict__ ba) {
  const int gr = blockIdx.x * 4 + (threadIdx.x >> 6);
  const int lane = threadIdx.x & 63;
  float* X0; const float* X1; const float* bias; int row;
  if (gr < BT_ROWS) { X0 = v0; X1 = v1; bias = bv; row = gr; }
  else              { X0 = a0; X1 = a1; bias = ba; row = gr - BT_ROWS; }
  float4 x = *(float4*)&X0[(size_t)row * 256 + lane * 4];
  const float4 y = *(const float4*)&X1[(size_t)row * 256 + lane * 4];
  const float4 b = *(const float4*)&bias[lane * 4];
  x.x += y.x + b.x; x.y += y.y + b.y; x.z += y.z + b.z; x.w += y.w + b.w;
  float s = x.x + x.y + x.z + x.w;
  float s2 = x.x * x.x + x.y * x.y + x.z * x.z + x.w * x.w;
  s = wave_bcast_sum(s);
  s2 = wave_bcast_sum(s2);
  const float mu = s * (1.0f / 256.0f);
  const float var = s2 * (1.0f / 256.0f) - mu * mu;
  const float inv = rsqrtf(var + 1e-5f);
  x.x = (x.x - mu) * inv; x.y = (x.y - mu) * inv;
  x.z = (x.z - mu) * inv; x.w = (x.w - mu) * inv;
  *(float4*)&X0[(size_t)row * 256 + lane * 4] = x;
}

// ---------- fused: fractional shift + window avg + l2norm(actx,v) + concat ----------
__global__ __launch_bounds__(256) void shift_norm(const float* __restrict__ a,
                                                  const float* __restrict__ v,
                                                  float* __restrict__ actx,
                                                  u16* __restrict__ xb,
                                                  const float* __restrict__ theta) {
  const int row = blockIdx.x * 4 + (threadIdx.x >> 6);
  const int lane = threadIdx.x & 63;
  const int d4 = lane * 4;
  const int bb = row >> 11;
  const int t = row & (T_SEQ - 1);
  const float th = fminf(fmaxf(theta[0], -12.0f), 12.0f);
  const float delta = 2.0f + 4.0f * (1.0f / (1.0f + expf(-th)));
  const float dl = fminf(fmaxf(delta, 0.0f), (float)(T_SEQ - 1));
  const float nf = floorf(dl);
  const float alpha = dl - nf;
  const int ni = (int)nf;
  const float center = fminf(fmaxf((float)t + delta, 0.0f), (float)t);
  float sx = 0, sy = 0, sz = 0, sw = 0, cnt = 0.0f;
  const float* ab = a + (size_t)bb * T_SEQ * 256;
#pragma unroll
  for (int j = 0; j < 6; j++) {
    const int tau = t - 5 + j;
    if (tau < 0) continue;
    if (fabsf((float)tau - center) > 5.0f) continue;
    cnt += 1.0f;
    const int i0 = min(max(tau - ni, 0), T_SEQ - 1);
    const int i1 = min(i0 + 1, T_SEQ - 1);
    const float4 a0 = *(const float4*)&ab[(size_t)i0 * 256 + d4];
    const float4 a1 = *(const float4*)&ab[(size_t)i1 * 256 + d4];
    sx += a0.x + alpha * (a1.x - a0.x);
    sy += a0.y + alpha * (a1.y - a0.y);
    sz += a0.z + alpha * (a1.z - a0.z);
    sw += a0.w + alpha * (a1.w - a0.w);
  }
  const float sc = 1.0f / fmaxf(cnt, 1e-8f);
  float4 o; o.x = sx * sc; o.y = sy * sc; o.z = sz * sc; o.w = sw * sc;
  *(float4*)&actx[(size_t)row * 256 + d4] = o;
  const float4 vv = *(const float4*)&v[(size_t)row * 256 + d4];
  float sa2 = o.x * o.x + o.y * o.y + o.z * o.z + o.w * o.w;
  float sv2 = vv.x * vv.x + vv.y * vv.y + vv.z * vv.z + vv.w * vv.w;
  sa2 = wave_bcast_sum(sa2);
  sv2 = wave_bcast_sum(sv2);
  const float ia = 1.0f / fmaxf(sqrtf(sa2), 1e-8f);
  const float iv = 1.0f / fmaxf(sqrtf(sv2), 1e-8f);
  const float anx = o.x * ia, any_ = o.y * ia, anz = o.z * ia, anw = o.w * ia;
  const float vnx = vv.x * iv, vny = vv.y * iv, vnz = vv.z * iv, vnw = vv.w * iv;
  u16* xr = xb + (size_t)row * 768;
  u32 pa[2] = {pkbf(anx, any_), pkbf(anz, anw)};
  u32 pv[2] = {pkbf(vnx, vny), pkbf(vnz, vnw)};
  u32 pp[2] = {pkbf(anx * vnx, any_ * vny), pkbf(anz * vnz, anw * vnw)};
  *(uint2*)&xr[d4] = *(uint2*)pa;
  *(uint2*)&xr[256 + d4] = *(uint2*)pv;
  *(uint2*)&xr[512 + d4] = *(uint2*)pp;
}

// ---------- gate + mix ----------
__global__ __launch_bounds__(256) void gate_mix(const float* __restrict__ logits,
                                                const float* __restrict__ b2,
                                                const float* __restrict__ actx,
                                                const float* __restrict__ v,
                                                float* __restrict__ out) {
  const int row = blockIdx.x * 4 + (threadIdx.x >> 6);
  const int lane = threadIdx.x & 63;
  const float l = fminf(fmaxf(logits[row] + b2[0], -12.0f), 12.0f);
  float g = 1.0f / (1.0f + expf(-l));
  g = fminf(fmaxf(g, 0.05f), 0.95f);
  const float4 aa = *(const float4*)&actx[(size_t)row * 256 + lane * 4];
  const float4 vv = *(const float4*)&v[(size_t)row * 256 + lane * 4];
  float4 o;
  o.x = g * aa.x + (1.0f - g) * vv.x;
  o.y = g * aa.y + (1.0f - g) * vv.y;
  o.z = g * aa.z + (1.0f - g) * vv.z;
  o.w = g * aa.w + (1.0f - g) * vv.w;
  *(float4*)&out[(size_t)row * 256 + lane * 4] = o;
}

// ---------- launch ----------
extern "C" void kernel_launch(void* const* d_in, const int* in_sizes, int n_in,
                              void* d_out, int out_size, void* d_ws, size_t ws_size,
                              hipStream_t stream) {
  const float* video = (const float*)d_in[0];
  const float* audio = (const float*)d_in[1];
  const float* Wv    = (const float*)d_in[2];
  const float* bv    = (const float*)d_in[3];
  const float* Wa    = (const float*)d_in[4];
  const float* ba    = (const float*)d_in[5];
  const float* theta = (const float*)d_in[6];
  const float* W1    = (const float*)d_in[7];
  const float* b1    = (const float*)d_in[8];
  const float* W2    = (const float*)d_in[9];
  const float* b2    = (const float*)d_in[10];
  float* out = (float*)d_out;
  char* ws = (char*)d_ws;

  const size_t OFF_WVT = 0;          // [256][1024] bf16 = 512 KB
  const size_t OFF_WAT = 524288;     // [256][768]  bf16 = 384 KB
  const size_t OFF_W1T = 917504;     // [1024][768] bf16 = 1.5 MB
  const size_t OFF_LOG = 2490368;    // [16384] f32 = 64 KB
  const size_t OFF_CV0 = 2555904;    // 16 MB (k-half 0; becomes v after ln2)
  const size_t OFF_CV1 = 19333120;   // 16 MB (k-half 1)
  const size_t OFF_CA0 = 36110336;   // 16 MB (becomes a after ln2)
  const size_t OFF_CA1 = 52887552;   // 16 MB
  const size_t OFF_ACTX= 69664768;   // 16 MB
  const size_t OFF_XB  = 86441984;   // [16384][768] bf16 = 24 MB  (end ~111 MB)

  u16* wvT = (u16*)(ws + OFF_WVT);
  u16* waT = (u16*)(ws + OFF_WAT);
  u16* w1T = (u16*)(ws + OFF_W1T);
  float* logits = (float*)(ws + OFF_LOG);
  float* Cv0  = (float*)(ws + OFF_CV0);
  float* Cv1  = (float*)(ws + OFF_CV1);
  float* Ca0  = (float*)(ws + OFF_CA0);
  float* Ca1  = (float*)(ws + OFF_CA1);
  float* actx = (float*)(ws + OFF_ACTX);
  u16* xb = (u16*)(ws + OFF_XB);
  float* v = Cv0;  // ln2 writes LN result in place
  float* a = Ca0;

  tcvt_all<<<1280, 256, 0, stream>>>(Wv, Wa, W1, wvT, waT, w1T, logits);
  gemm_proj<<<2048, 256, 0, stream>>>(video, audio, wvT, waT, Cv0, Cv1, Ca0, Ca1);
  ln2<<<2 * BT_ROWS / 4, 256, 0, stream>>>(Cv0, Cv1, Ca0, Ca1, bv, ba);
  shift_norm<<<BT_ROWS / 4, 256, 0, stream>>>(a, v, actx, xb, theta);
  gemm_gelu_w2<<<dim3(8, BT_ROWS / 64), 256, 0, stream>>>(xb, w1T, b1, W2, logits);
  gate_mix<<<BT_ROWS / 4, 256, 0, stream>>>(logits, b2, actx, v, out);
}

// Round 9
// 248.683 us; speedup vs baseline: 2.5177x; 1.0483x over previous
//
#include <hip/hip_runtime.h>
#include <cstdint>
#include <cstddef>

typedef unsigned short u16;
typedef unsigned int u32;
typedef __attribute__((ext_vector_type(8))) short short8;
typedef __attribute__((ext_vector_type(4))) float f32x4;

#define T_SEQ 2048
#define BT_ROWS 16384

// ---------- helpers ----------
__device__ __forceinline__ u16 f2bf(float x) {
  union { float f; u32 u; } v; v.f = x;
  u32 r = v.u + 0x7fffu + ((v.u >> 16) & 1u);
  return (u16)(r >> 16);
}
// pack two floats -> two bf16 in one u32 (lo in low half)
__device__ __forceinline__ u32 pkbf(float lo, float hi) {
  union { float f; u32 u; } a, b; a.f = lo; b.f = hi;
  const u32 ra = a.u + 0x7fffu + ((a.u >> 16) & 1u);
  const u32 rb = b.u + 0x7fffu + ((b.u >> 16) & 1u);
  return __builtin_amdgcn_perm(rb, ra, 0x07060302);
}
__device__ __forceinline__ float wave_bcast_sum(float x) {
#pragma unroll
  for (int off = 32; off > 0; off >>= 1) x += __shfl_down(x, off);
  return __shfl(x, 0);
}
__device__ __forceinline__ void gl_lds16(const void* g, void* l) {
  __builtin_amdgcn_global_load_lds((const __attribute__((address_space(1))) u32*)g,
                                   (__attribute__((address_space(3))) u32*)l, 16, 0, 0);
}
// tanh-form GELU; |diff| vs erf ~3e-4
__device__ __forceinline__ float gelu_f(float x) {
  float z = 1.5957691216057308f * x * (1.0f + 0.044715f * x * x);
  float e = __expf(z);
  return x - x * __builtin_amdgcn_rcpf(1.0f + e);
}

// ---------- transpose+convert all 3 weights + zero logits ----------
__global__ __launch_bounds__(256) void tcvt_all(const float* __restrict__ Wv,
                                                const float* __restrict__ Wa,
                                                const float* __restrict__ W1,
                                                u16* __restrict__ wvT,
                                                u16* __restrict__ waT,
                                                u16* __restrict__ w1T,
                                                float* __restrict__ logits) {
  int b = blockIdx.x;
  if (b >= 1216) {  // 64 blocks zero the 16384-float logits buffer
    logits[(b - 1216) * 256 + threadIdx.x] = 0.0f;
    return;
  }
  __shared__ float tile[32][33];
  const float* in; u16* out; int K, N, bx, by;
  if (b < 256)      { in = Wv; out = wvT; K = 1024; N = 256;  bx = b & 31;  by = b >> 5; }
  else if (b < 448) { b -= 256; in = Wa; out = waT; K = 768; N = 256;  bx = b % 24; by = b / 24; }
  else              { b -= 448; in = W1; out = w1T; K = 768; N = 1024; bx = b % 24; by = b / 24; }
  const int k0 = bx * 32, n0 = by * 32;
  const int tx = threadIdx.x & 31, ty = threadIdx.x >> 5;
#pragma unroll
  for (int r = 0; r < 4; r++)
    tile[ty + r * 8][tx] = in[(size_t)(k0 + ty + r * 8) * N + n0 + tx];
  __syncthreads();
#pragma unroll
  for (int r = 0; r < 4; r++)
    out[(size_t)(n0 + ty + r * 8) * K + k0 + tx] = f2bf(tile[tx][ty + r * 8]);
}

// ---------- projection GEMM with FUSED LayerNorm epilogue ----------
// Tile 32x256 (full N -> block owns whole rows), BK=64, LDS 40KB -> 4 blocks/CU.
// C = LN(A @ Bt^T + bias) written directly. Blocks 0..511 video, 512..1023 audio.
__global__ __launch_bounds__(256, 4) void proj_ln(const float* __restrict__ Vin,
                                                  const float* __restrict__ Ain,
                                                  const u16* __restrict__ wvT,
                                                  const u16* __restrict__ waT,
                                                  const float* __restrict__ bv,
                                                  const float* __restrict__ ba,
                                                  float* __restrict__ vOut,
                                                  float* __restrict__ aOut) {
  __shared__ float Asf[32 * 64];   // 8 KB
  __shared__ u16 Bs[256 * 64];     // 32 KB
  int b = blockIdx.x;
  const float* A; const u16* Bt; const float* bias; float* C; int K;
  if (b < 512) { A = Vin; Bt = wvT; bias = bv; C = vOut; K = 1024; }
  else         { b -= 512; A = Ain; Bt = waT; bias = ba; C = aOut; K = 768; }
  const int m0 = b * 32;
  const int tid = threadIdx.x;
  const int wave = tid >> 6, lane = tid & 63, qm = lane & 15, quad = lane >> 4;
  const int cw = wave * 64;   // each wave owns a 64-col quarter, all 32 rows

  // A staging (r4-verified xor-16 swizzle): chunk c -> row c>>4, part (c&15)^(row&15)
  const int arow = tid >> 4;                  // 0..15
  const int apart = (tid & 15) ^ (arow & 15);
  const float* Ap0 = A + (size_t)(m0 + arow) * K + apart * 4;
  const float* Ap1 = Ap0 + (size_t)16 * K;    // rows 16..31, same swizzle
  // B staging (r4-verified xor-8 swizzle): chunk c -> row c>>3, part (c&7)^(row&7)
  const int brow = tid >> 3;                  // 0..31
  const int bpart = (tid & 7) ^ (brow & 7);
  const u16* Bp[8];
#pragma unroll
  for (int g = 0; g < 8; g++)
    Bp[g] = Bt + (size_t)(brow + g * 32) * K + bpart * 8;

  f32x4 acc[2][4] = {};
  for (int kt = 0; kt < K; kt += 64) {
    gl_lds16(Ap0 + kt, &Asf[tid * 4]);
    gl_lds16(Ap1 + kt, &Asf[(tid + 256) * 4]);
#pragma unroll
    for (int g = 0; g < 8; g++) gl_lds16(Bp[g] + kt, &Bs[(tid + g * 256) * 8]);
    __syncthreads();
#pragma unroll
    for (int s = 0; s < 2; s++) {
      short8 af[2], bfr[4];
#pragma unroll
      for (int i = 0; i < 2; i++) {
        const int r = i * 16 + qm;
        const int pb = s * 8 + quad * 2;
        const float4 f0 = *(const float4*)&Asf[r * 64 + ((pb) ^ (r & 15)) * 4];
        const float4 f1 = *(const float4*)&Asf[r * 64 + ((pb + 1) ^ (r & 15)) * 4];
        u32 w[4] = {pkbf(f0.x, f0.y), pkbf(f0.z, f0.w), pkbf(f1.x, f1.y), pkbf(f1.z, f1.w)};
        af[i] = *(short8*)w;
      }
#pragma unroll
      for (int j = 0; j < 4; j++) {
        const int r = cw + j * 16 + qm;
        bfr[j] = *(const short8*)&Bs[r * 64 + ((s * 4 + quad) ^ (r & 7)) * 8];
      }
#pragma unroll
      for (int i = 0; i < 2; i++)
#pragma unroll
        for (int j = 0; j < 4; j++)
          acc[i][j] = __builtin_amdgcn_mfma_f32_16x16x32_bf16(af[i], bfr[j], acc[i][j], 0, 0, 0);
    }
    __syncthreads();
  }

  // ---- fused bias + LayerNorm epilogue ----
  // add bias (per-col) first
  float bcol[4];
#pragma unroll
  for (int j = 0; j < 4; j++) bcol[j] = bias[cw + j * 16 + qm];
#pragma unroll
  for (int i = 0; i < 2; i++)
#pragma unroll
    for (int j = 0; j < 4; j++)
#pragma unroll
      for (int r = 0; r < 4; r++)
        acc[i][j][r] += bcol[j];
  // per-row partial sums over this wave's 64 cols (4 cols/lane x 16 qm lanes)
  float s1[2][4], s2[2][4];
#pragma unroll
  for (int i = 0; i < 2; i++)
#pragma unroll
    for (int r = 0; r < 4; r++) {
      float a1 = 0, a2 = 0;
#pragma unroll
      for (int j = 0; j < 4; j++) { a1 += acc[i][j][r]; a2 += acc[i][j][r] * acc[i][j][r]; }
#pragma unroll
      for (int off = 1; off < 16; off <<= 1) {
        a1 += __shfl_xor(a1, off);
        a2 += __shfl_xor(a2, off);
      }
      s1[i][r] = a1; s2[i][r] = a2;
    }
  // cross-wave reduce via LDS: red[row][wave*2 + {0,1}]
  float* red = Asf;  // safe: K-loop ended with __syncthreads
  if (qm == 0) {
#pragma unroll
    for (int i = 0; i < 2; i++)
#pragma unroll
      for (int r = 0; r < 4; r++) {
        const int row = i * 16 + quad * 4 + r;
        red[row * 8 + wave * 2] = s1[i][r];
        red[row * 8 + wave * 2 + 1] = s2[i][r];
      }
  }
  __syncthreads();
#pragma unroll
  for (int i = 0; i < 2; i++)
#pragma unroll
    for (int r = 0; r < 4; r++) {
      const int row = i * 16 + quad * 4 + r;   // D: row = quad*4 + reg (+ i*16)
      const float4 q1 = *(const float4*)&red[row * 8];
      const float4 q2 = *(const float4*)&red[row * 8 + 4];
      const float st = q1.x + q1.z + q2.x + q2.z;
      const float st2 = q1.y + q1.w + q2.y + q2.w;
      const float mu = st * (1.0f / 256.0f);
      const float var = st2 * (1.0f / 256.0f) - mu * mu;
      const float inv = rsqrtf(var + 1e-5f);
#pragma unroll
      for (int j = 0; j < 4; j++)
        C[(size_t)(m0 + row) * 256 + cw + j * 16 + qm] = (acc[i][j][r] - mu) * inv;
    }
}

// ---------- MLP GEMM (r4-proven): tile 64x128, BK=64, fused bias+GELU+W2 -> atomic logits ----------
__global__ __launch_bounds__(256, 6) void gemm_gelu_w2(const u16* __restrict__ Axb,
                                                       const u16* __restrict__ Bt,
                                                       const float* __restrict__ b1,
                                                       const float* __restrict__ W2,
                                                       float* __restrict__ logits) {
  constexpr int K = 768;
  __shared__ u16 As[64 * 64];    // 8 KB
  __shared__ u16 Bs[128 * 64];   // 16 KB
  const int tid = threadIdx.x;
  const int n0 = blockIdx.x * 128;   // x = n: consecutive blocks share A m-tile
  const int m0 = blockIdx.y * 64;
  const int wave = tid >> 6, lane = tid & 63, qm = lane & 15, quad = lane >> 4;
  const int rw = (wave >> 1) * 32, cw = (wave & 1) * 64;

  const int crow = tid >> 3;
  const int cpart = (tid & 7) ^ (crow & 7);
  const u16* Ap[2];
#pragma unroll
  for (int g = 0; g < 2; g++)
    Ap[g] = Axb + (size_t)(m0 + crow + g * 32) * K + cpart * 8;
  const u16* Bp[4];
#pragma unroll
  for (int g = 0; g < 4; g++)
    Bp[g] = Bt + (size_t)(n0 + crow + g * 32) * K + cpart * 8;

  f32x4 acc[2][4] = {};
  for (int kt = 0; kt < K; kt += 64) {
#pragma unroll
    for (int g = 0; g < 2; g++) gl_lds16(Ap[g] + kt, &As[(tid + g * 256) * 8]);
#pragma unroll
    for (int g = 0; g < 4; g++) gl_lds16(Bp[g] + kt, &Bs[(tid + g * 256) * 8]);
    __syncthreads();
#pragma unroll
    for (int s = 0; s < 2; s++) {
      short8 af[2], bfr[4];
#pragma unroll
      for (int i = 0; i < 2; i++) {
        const int r = rw + i * 16 + qm;
        af[i] = *(const short8*)&As[r * 64 + ((s * 4 + quad) ^ (r & 7)) * 8];
      }
#pragma unroll
      for (int j = 0; j < 4; j++) {
        const int r = cw + j * 16 + qm;
        bfr[j] = *(const short8*)&Bs[r * 64 + ((s * 4 + quad) ^ (r & 7)) * 8];
      }
#pragma unroll
      for (int i = 0; i < 2; i++)
#pragma unroll
        for (int j = 0; j < 4; j++)
          acc[i][j] = __builtin_amdgcn_mfma_f32_16x16x32_bf16(af[i], bfr[j], acc[i][j], 0, 0, 0);
    }
    __syncthreads();
  }

  float w2j[4], bc[4];
#pragma unroll
  for (int j = 0; j < 4; j++) {
    const int col = n0 + cw + j * 16 + qm;
    w2j[j] = W2[col];
    bc[j] = b1[col];
  }
#pragma unroll
  for (int i = 0; i < 2; i++) {
#pragma unroll
    for (int r = 0; r < 4; r++) {
      float p = 0.0f;
#pragma unroll
      for (int j = 0; j < 4; j++)
        p += gelu_f(acc[i][j][r] + bc[j]) * w2j[j];
      p += __shfl_xor(p, 1);
      p += __shfl_xor(p, 2);
      p += __shfl_xor(p, 4);
      p += __shfl_xor(p, 8);
      if (qm == 0)
        atomicAdd(&logits[m0 + rw + i * 16 + quad * 4 + r], p);
    }
  }
}

// ---------- fused: fractional shift + window avg + l2norm(actx,v) + concat ----------
__global__ __launch_bounds__(256) void shift_norm(const float* __restrict__ a,
                                                  const float* __restrict__ v,
                                                  float* __restrict__ actx,
                                                  u16* __restrict__ xb,
                                                  const float* __restrict__ theta) {
  const int row = blockIdx.x * 4 + (threadIdx.x >> 6);
  const int lane = threadIdx.x & 63;
  const int d4 = lane * 4;
  const int bb = row >> 11;
  const int t = row & (T_SEQ - 1);
  const float th = fminf(fmaxf(theta[0], -12.0f), 12.0f);
  const float delta = 2.0f + 4.0f * (1.0f / (1.0f + expf(-th)));
  const float dl = fminf(fmaxf(delta, 0.0f), (float)(T_SEQ - 1));
  const float nf = floorf(dl);
  const float alpha = dl - nf;
  const int ni = (int)nf;
  const float center = fminf(fmaxf((float)t + delta, 0.0f), (float)t);
  float sx = 0, sy = 0, sz = 0, sw = 0, cnt = 0.0f;
  const float* ab = a + (size_t)bb * T_SEQ * 256;
#pragma unroll
  for (int j = 0; j < 6; j++) {
    const int tau = t - 5 + j;
    if (tau < 0) continue;
    if (fabsf((float)tau - center) > 5.0f) continue;
    cnt += 1.0f;
    const int i0 = min(max(tau - ni, 0), T_SEQ - 1);
    const int i1 = min(i0 + 1, T_SEQ - 1);
    const float4 a0 = *(const float4*)&ab[(size_t)i0 * 256 + d4];
    const float4 a1 = *(const float4*)&ab[(size_t)i1 * 256 + d4];
    sx += a0.x + alpha * (a1.x - a0.x);
    sy += a0.y + alpha * (a1.y - a0.y);
    sz += a0.z + alpha * (a1.z - a0.z);
    sw += a0.w + alpha * (a1.w - a0.w);
  }
  const float sc = 1.0f / fmaxf(cnt, 1e-8f);
  float4 o; o.x = sx * sc; o.y = sy * sc; o.z = sz * sc; o.w = sw * sc;
  *(float4*)&actx[(size_t)row * 256 + d4] = o;
  const float4 vv = *(const float4*)&v[(size_t)row * 256 + d4];
  float sa2 = o.x * o.x + o.y * o.y + o.z * o.z + o.w * o.w;
  float sv2 = vv.x * vv.x + vv.y * vv.y + vv.z * vv.z + vv.w * vv.w;
  sa2 = wave_bcast_sum(sa2);
  sv2 = wave_bcast_sum(sv2);
  const float ia = 1.0f / fmaxf(sqrtf(sa2), 1e-8f);
  const float iv = 1.0f / fmaxf(sqrtf(sv2), 1e-8f);
  const float anx = o.x * ia, any_ = o.y * ia, anz = o.z * ia, anw = o.w * ia;
  const float vnx = vv.x * iv, vny = vv.y * iv, vnz = vv.z * iv, vnw = vv.w * iv;
  u16* xr = xb + (size_t)row * 768;
  u32 pa[2] = {pkbf(anx, any_), pkbf(anz, anw)};
  u32 pv[2] = {pkbf(vnx, vny), pkbf(vnz, vnw)};
  u32 pp[2] = {pkbf(anx * vnx, any_ * vny), pkbf(anz * vnz, anw * vnw)};
  *(uint2*)&xr[d4] = *(uint2*)pa;
  *(uint2*)&xr[256 + d4] = *(uint2*)pv;
  *(uint2*)&xr[512 + d4] = *(uint2*)pp;
}

// ---------- gate + mix ----------
__global__ __launch_bounds__(256) void gate_mix(const float* __restrict__ logits,
                                                const float* __restrict__ b2,
                                                const float* __restrict__ actx,
                                                const float* __restrict__ v,
                                                float* __restrict__ out) {
  const int row = blockIdx.x * 4 + (threadIdx.x >> 6);
  const int lane = threadIdx.x & 63;
  const float l = fminf(fmaxf(logits[row] + b2[0], -12.0f), 12.0f);
  float g = 1.0f / (1.0f + expf(-l));
  g = fminf(fmaxf(g, 0.05f), 0.95f);
  const float4 aa = *(const float4*)&actx[(size_t)row * 256 + lane * 4];
  const float4 vv = *(const float4*)&v[(size_t)row * 256 + lane * 4];
  float4 o;
  o.x = g * aa.x + (1.0f - g) * vv.x;
  o.y = g * aa.y + (1.0f - g) * vv.y;
  o.z = g * aa.z + (1.0f - g) * vv.z;
  o.w = g * aa.w + (1.0f - g) * vv.w;
  *(float4*)&out[(size_t)row * 256 + lane * 4] = o;
}

// ---------- launch ----------
extern "C" void kernel_launch(void* const* d_in, const int* in_sizes, int n_in,
                              void* d_out, int out_size, void* d_ws, size_t ws_size,
                              hipStream_t stream) {
  const float* video = (const float*)d_in[0];
  const float* audio = (const float*)d_in[1];
  const float* Wv    = (const float*)d_in[2];
  const float* bv    = (const float*)d_in[3];
  const float* Wa    = (const float*)d_in[4];
  const float* ba    = (const float*)d_in[5];
  const float* theta = (const float*)d_in[6];
  const float* W1    = (const float*)d_in[7];
  const float* b1    = (const float*)d_in[8];
  const float* W2    = (const float*)d_in[9];
  const float* b2    = (const float*)d_in[10];
  float* out = (float*)d_out;
  char* ws = (char*)d_ws;

  const size_t OFF_WVT = 0;          // [256][1024] bf16 = 512 KB
  const size_t OFF_WAT = 524288;     // [256][768]  bf16 = 384 KB
  const size_t OFF_W1T = 917504;     // [1024][768] bf16 = 1.5 MB
  const size_t OFF_LOG = 2490368;    // [16384] f32 = 64 KB
  const size_t OFF_V   = 2555904;    // [16384][256] f32 = 16 MB (LN'd v)
  const size_t OFF_A   = 19333120;   // [16384][256] f32 = 16 MB (LN'd a)
  const size_t OFF_ACTX= 36110336;   // [16384][256] f32 = 16 MB
  const size_t OFF_XB  = 52887552;   // [16384][768] bf16 = 24 MB

  u16* wvT = (u16*)(ws + OFF_WVT);
  u16* waT = (u16*)(ws + OFF_WAT);
  u16* w1T = (u16*)(ws + OFF_W1T);
  float* logits = (float*)(ws + OFF_LOG);
  float* v    = (float*)(ws + OFF_V);
  float* a    = (float*)(ws + OFF_A);
  float* actx = (float*)(ws + OFF_ACTX);
  u16* xb = (u16*)(ws + OFF_XB);

  tcvt_all<<<1280, 256, 0, stream>>>(Wv, Wa, W1, wvT, waT, w1T, logits);
  proj_ln<<<1024, 256, 0, stream>>>(video, audio, wvT, waT, bv, ba, v, a);
  shift_norm<<<BT_ROWS / 4, 256, 0, stream>>>(a, v, actx, xb, theta);
  gemm_gelu_w2<<<dim3(8, BT_ROWS / 64), 256, 0, stream>>>(xb, w1T, b1, W2, logits);
  gate_mix<<<BT_ROWS / 4, 256, 0, stream>>>(logits, b2, actx, v, out);
}

// Round 10
// 246.459 us; speedup vs baseline: 2.5404x; 1.0090x over previous
//
#include <hip/hip_runtime.h>
#include <cstdint>
#include <cstddef>

typedef unsigned short u16;
typedef unsigned int u32;
typedef __attribute__((ext_vector_type(8))) short short8;
typedef __attribute__((ext_vector_type(4))) float f32x4;

#define T_SEQ 2048
#define BT_ROWS 16384

// ---------- helpers ----------
__device__ __forceinline__ u16 f2bf(float x) {
  union { float f; u32 u; } v; v.f = x;
  u32 r = v.u + 0x7fffu + ((v.u >> 16) & 1u);
  return (u16)(r >> 16);
}
// pack two floats -> two bf16 in one u32 (lo in low half)
__device__ __forceinline__ u32 pkbf(float lo, float hi) {
  union { float f; u32 u; } a, b; a.f = lo; b.f = hi;
  const u32 ra = a.u + 0x7fffu + ((a.u >> 16) & 1u);
  const u32 rb = b.u + 0x7fffu + ((b.u >> 16) & 1u);
  return __builtin_amdgcn_perm(rb, ra, 0x07060302);
}
__device__ __forceinline__ float wave_bcast_sum(float x) {
#pragma unroll
  for (int off = 32; off > 0; off >>= 1) x += __shfl_down(x, off);
  return __shfl(x, 0);
}
__device__ __forceinline__ void gl_lds16(const void* g, void* l) {
  __builtin_amdgcn_global_load_lds((const __attribute__((address_space(1))) u32*)g,
                                   (__attribute__((address_space(3))) u32*)l, 16, 0, 0);
}
// tanh-form GELU; |diff| vs erf ~3e-4
__device__ __forceinline__ float gelu_f(float x) {
  float z = 1.5957691216057308f * x * (1.0f + 0.044715f * x * x);
  float e = __expf(z);
  return x - x * __builtin_amdgcn_rcpf(1.0f + e);
}

// ---------- transpose+convert all 3 weights + zero logits ----------
__global__ __launch_bounds__(256) void tcvt_all(const float* __restrict__ Wv,
                                                const float* __restrict__ Wa,
                                                const float* __restrict__ W1,
                                                u16* __restrict__ wvT,
                                                u16* __restrict__ waT,
                                                u16* __restrict__ w1T,
                                                float* __restrict__ logits) {
  int b = blockIdx.x;
  if (b >= 1216) {  // 64 blocks zero the 16384-float logits buffer
    logits[(b - 1216) * 256 + threadIdx.x] = 0.0f;
    return;
  }
  __shared__ float tile[32][33];
  const float* in; u16* out; int K, N, bx, by;
  if (b < 256)      { in = Wv; out = wvT; K = 1024; N = 256;  bx = b & 31;  by = b >> 5; }
  else if (b < 448) { b -= 256; in = Wa; out = waT; K = 768; N = 256;  bx = b % 24; by = b / 24; }
  else              { b -= 448; in = W1; out = w1T; K = 768; N = 1024; bx = b % 24; by = b / 24; }
  const int k0 = bx * 32, n0 = by * 32;
  const int tx = threadIdx.x & 31, ty = threadIdx.x >> 5;
#pragma unroll
  for (int r = 0; r < 4; r++)
    tile[ty + r * 8][tx] = in[(size_t)(k0 + ty + r * 8) * N + n0 + tx];
  __syncthreads();
#pragma unroll
  for (int r = 0; r < 4; r++)
    out[(size_t)(n0 + ty + r * 8) * K + k0 + tx] = f2bf(tile[tx][ty + r * 8]);
}

// ---------- projection GEMM with FUSED LayerNorm, tile 64x256, acc 4x4 ----------
// Block owns 64 full rows. LDS 48 KB -> 3/CU; grid 512 (video 256 + audio 256).
// 32 MFMA per barrier stage (2x r9) — m93 lever.
__global__ __launch_bounds__(256, 3) void proj_ln(const float* __restrict__ Vin,
                                                  const float* __restrict__ Ain,
                                                  const u16* __restrict__ wvT,
                                                  const u16* __restrict__ waT,
                                                  const float* __restrict__ bv,
                                                  const float* __restrict__ ba,
                                                  float* __restrict__ vOut,
                                                  float* __restrict__ aOut) {
  __shared__ float Asf[64 * 64];   // 16 KB
  __shared__ u16 Bs[256 * 64];     // 32 KB
  int b = blockIdx.x;
  const float* A; const u16* Bt; const float* bias; float* C; int K;
  if (b < 256) { A = Vin; Bt = wvT; bias = bv; C = vOut; K = 1024; }
  else         { b -= 256; A = Ain; Bt = waT; bias = ba; C = aOut; K = 768; }
  const int m0 = b * 64;
  const int tid = threadIdx.x;
  const int wave = tid >> 6, lane = tid & 63, qm = lane & 15, quad = lane >> 4;
  const int cw = wave * 64;   // wave owns a 64-col quarter, all 64 rows

  // A staging (xor-16 swizzle, verified 0-conflict): chunk -> row (tid>>4)+g*16
  const int arow = tid >> 4;
  const int apart = (tid & 15) ^ (arow & 15);
  const float* Ap[4];
#pragma unroll
  for (int g = 0; g < 4; g++)
    Ap[g] = A + (size_t)(m0 + arow + g * 16) * K + apart * 4;
  // B staging (xor-8 swizzle, verified): rows (tid>>3)+g*32, g 0..7 -> all 256
  const int brow = tid >> 3;
  const int bpart = (tid & 7) ^ (brow & 7);
  const u16* Bp[8];
#pragma unroll
  for (int g = 0; g < 8; g++)
    Bp[g] = Bt + (size_t)(brow + g * 32) * K + bpart * 8;

  f32x4 acc[4][4] = {};
  for (int kt = 0; kt < K; kt += 64) {
#pragma unroll
    for (int g = 0; g < 4; g++) gl_lds16(Ap[g] + kt, &Asf[(tid + g * 256) * 4]);
#pragma unroll
    for (int g = 0; g < 8; g++) gl_lds16(Bp[g] + kt, &Bs[(tid + g * 256) * 8]);
    __syncthreads();
#pragma unroll
    for (int s = 0; s < 2; s++) {
      short8 af[4], bfr[4];
#pragma unroll
      for (int i = 0; i < 4; i++) {
        const int r = i * 16 + qm;
        const int pb = s * 8 + quad * 2;
        const float4 f0 = *(const float4*)&Asf[r * 64 + ((pb) ^ (r & 15)) * 4];
        const float4 f1 = *(const float4*)&Asf[r * 64 + ((pb + 1) ^ (r & 15)) * 4];
        u32 w[4] = {pkbf(f0.x, f0.y), pkbf(f0.z, f0.w), pkbf(f1.x, f1.y), pkbf(f1.z, f1.w)};
        af[i] = *(short8*)w;
      }
#pragma unroll
      for (int j = 0; j < 4; j++) {
        const int r = cw + j * 16 + qm;
        bfr[j] = *(const short8*)&Bs[r * 64 + ((s * 4 + quad) ^ (r & 7)) * 8];
      }
#pragma unroll
      for (int i = 0; i < 4; i++)
#pragma unroll
        for (int j = 0; j < 4; j++)
          acc[i][j] = __builtin_amdgcn_mfma_f32_16x16x32_bf16(af[i], bfr[j], acc[i][j], 0, 0, 0);
    }
    __syncthreads();
  }

  // ---- fused bias + LayerNorm epilogue over 64 rows ----
  float bcol[4];
#pragma unroll
  for (int j = 0; j < 4; j++) bcol[j] = bias[cw + j * 16 + qm];
#pragma unroll
  for (int i = 0; i < 4; i++)
#pragma unroll
    for (int j = 0; j < 4; j++)
#pragma unroll
      for (int r = 0; r < 4; r++)
        acc[i][j][r] += bcol[j];
  float s1[4][4], s2[4][4];
#pragma unroll
  for (int i = 0; i < 4; i++)
#pragma unroll
    for (int r = 0; r < 4; r++) {
      float a1 = 0, a2 = 0;
#pragma unroll
      for (int j = 0; j < 4; j++) { a1 += acc[i][j][r]; a2 += acc[i][j][r] * acc[i][j][r]; }
#pragma unroll
      for (int off = 1; off < 16; off <<= 1) {
        a1 += __shfl_xor(a1, off);
        a2 += __shfl_xor(a2, off);
      }
      s1[i][r] = a1; s2[i][r] = a2;
    }
  float* red = Asf;  // safe: K-loop ended with __syncthreads
  if (qm == 0) {
#pragma unroll
    for (int i = 0; i < 4; i++)
#pragma unroll
      for (int r = 0; r < 4; r++) {
        const int row = i * 16 + quad * 4 + r;
        red[row * 8 + wave * 2] = s1[i][r];
        red[row * 8 + wave * 2 + 1] = s2[i][r];
      }
  }
  __syncthreads();
#pragma unroll
  for (int i = 0; i < 4; i++)
#pragma unroll
    for (int r = 0; r < 4; r++) {
      const int row = i * 16 + quad * 4 + r;   // D: row = quad*4 + reg (+ i*16)
      const float4 q1 = *(const float4*)&red[row * 8];
      const float4 q2 = *(const float4*)&red[row * 8 + 4];
      const float st = q1.x + q1.z + q2.x + q2.z;
      const float st2 = q1.y + q1.w + q2.y + q2.w;
      const float mu = st * (1.0f / 256.0f);
      const float var = st2 * (1.0f / 256.0f) - mu * mu;
      const float inv = rsqrtf(var + 1e-5f);
#pragma unroll
      for (int j = 0; j < 4; j++)
        C[(size_t)(m0 + row) * 256 + cw + j * 16 + qm] = (acc[i][j][r] - mu) * inv;
    }
}

// ---------- MLP GEMM: m97 shape 128x128, BK=64, acc 4x4, fused bias+GELU+W2 ----------
__global__ __launch_bounds__(256, 3) void gemm_gelu_w2(const u16* __restrict__ Axb,
                                                       const u16* __restrict__ Bt,
                                                       const float* __restrict__ b1,
                                                       const float* __restrict__ W2,
                                                       float* __restrict__ logits) {
  constexpr int K = 768;
  __shared__ u16 As[128 * 64];   // 16 KB
  __shared__ u16 Bs[128 * 64];   // 16 KB
  const int tid = threadIdx.x;
  const int n0 = blockIdx.x * 128;   // x = n: consecutive blocks share A m-tile
  const int m0 = blockIdx.y * 128;
  const int wave = tid >> 6, lane = tid & 63, qm = lane & 15, quad = lane >> 4;
  const int rw = (wave >> 1) * 64, cw = (wave & 1) * 64;

  const int crow = tid >> 3;
  const int cpart = (tid & 7) ^ (crow & 7);
  const u16* Ap[4];
  const u16* Bp[4];
#pragma unroll
  for (int g = 0; g < 4; g++) {
    Ap[g] = Axb + (size_t)(m0 + crow + g * 32) * K + cpart * 8;
    Bp[g] = Bt + (size_t)(n0 + crow + g * 32) * K + cpart * 8;
  }

  f32x4 acc[4][4] = {};
  for (int kt = 0; kt < K; kt += 64) {
#pragma unroll
    for (int g = 0; g < 4; g++) gl_lds16(Ap[g] + kt, &As[(tid + g * 256) * 8]);
#pragma unroll
    for (int g = 0; g < 4; g++) gl_lds16(Bp[g] + kt, &Bs[(tid + g * 256) * 8]);
    __syncthreads();
#pragma unroll
    for (int s = 0; s < 2; s++) {
      short8 af[4], bfr[4];
#pragma unroll
      for (int i = 0; i < 4; i++) {
        const int r = rw + i * 16 + qm;
        af[i] = *(const short8*)&As[r * 64 + ((s * 4 + quad) ^ (r & 7)) * 8];
      }
#pragma unroll
      for (int j = 0; j < 4; j++) {
        const int r = cw + j * 16 + qm;
        bfr[j] = *(const short8*)&Bs[r * 64 + ((s * 4 + quad) ^ (r & 7)) * 8];
      }
#pragma unroll
      for (int i = 0; i < 4; i++)
#pragma unroll
        for (int j = 0; j < 4; j++)
          acc[i][j] = __builtin_amdgcn_mfma_f32_16x16x32_bf16(af[i], bfr[j], acc[i][j], 0, 0, 0);
    }
    __syncthreads();
  }

  // epilogue: partial logit = sum_j gelu(acc+b1)*W2; reduce over qm lanes; 1 atomic/row
  float w2j[4], bc[4];
#pragma unroll
  for (int j = 0; j < 4; j++) {
    const int col = n0 + cw + j * 16 + qm;
    w2j[j] = W2[col];
    bc[j] = b1[col];
  }
#pragma unroll
  for (int i = 0; i < 4; i++) {
#pragma unroll
    for (int r = 0; r < 4; r++) {
      float p = 0.0f;
#pragma unroll
      for (int j = 0; j < 4; j++)
        p += gelu_f(acc[i][j][r] + bc[j]) * w2j[j];
      p += __shfl_xor(p, 1);
      p += __shfl_xor(p, 2);
      p += __shfl_xor(p, 4);
      p += __shfl_xor(p, 8);
      if (qm == 0)
        atomicAdd(&logits[m0 + rw + i * 16 + quad * 4 + r], p);
    }
  }
}

// ---------- fused: fractional shift + window avg + l2norm(actx,v) + concat ----------
__global__ __launch_bounds__(256) void shift_norm(const float* __restrict__ a,
                                                  const float* __restrict__ v,
                                                  float* __restrict__ actx,
                                                  u16* __restrict__ xb,
                                                  const float* __restrict__ theta) {
  const int row = blockIdx.x * 4 + (threadIdx.x >> 6);
  const int lane = threadIdx.x & 63;
  const int d4 = lane * 4;
  const int bb = row >> 11;
  const int t = row & (T_SEQ - 1);
  const float th = fminf(fmaxf(theta[0], -12.0f), 12.0f);
  const float delta = 2.0f + 4.0f * (1.0f / (1.0f + expf(-th)));
  const float dl = fminf(fmaxf(delta, 0.0f), (float)(T_SEQ - 1));
  const float nf = floorf(dl);
  const float alpha = dl - nf;
  const int ni = (int)nf;
  const float center = fminf(fmaxf((float)t + delta, 0.0f), (float)t);
  float sx = 0, sy = 0, sz = 0, sw = 0, cnt = 0.0f;
  const float* ab = a + (size_t)bb * T_SEQ * 256;
#pragma unroll
  for (int j = 0; j < 6; j++) {
    const int tau = t - 5 + j;
    if (tau < 0) continue;
    if (fabsf((float)tau - center) > 5.0f) continue;
    cnt += 1.0f;
    const int i0 = min(max(tau - ni, 0), T_SEQ - 1);
    const int i1 = min(i0 + 1, T_SEQ - 1);
    const float4 a0 = *(const float4*)&ab[(size_t)i0 * 256 + d4];
    const float4 a1 = *(const float4*)&ab[(size_t)i1 * 256 + d4];
    sx += a0.x + alpha * (a1.x - a0.x);
    sy += a0.y + alpha * (a1.y - a0.y);
    sz += a0.z + alpha * (a1.z - a0.z);
    sw += a0.w + alpha * (a1.w - a0.w);
  }
  const float sc = 1.0f / fmaxf(cnt, 1e-8f);
  float4 o; o.x = sx * sc; o.y = sy * sc; o.z = sz * sc; o.w = sw * sc;
  *(float4*)&actx[(size_t)row * 256 + d4] = o;
  const float4 vv = *(const float4*)&v[(size_t)row * 256 + d4];
  float sa2 = o.x * o.x + o.y * o.y + o.z * o.z + o.w * o.w;
  float sv2 = vv.x * vv.x + vv.y * vv.y + vv.z * vv.z + vv.w * vv.w;
  sa2 = wave_bcast_sum(sa2);
  sv2 = wave_bcast_sum(sv2);
  const float ia = 1.0f / fmaxf(sqrtf(sa2), 1e-8f);
  const float iv = 1.0f / fmaxf(sqrtf(sv2), 1e-8f);
  const float anx = o.x * ia, any_ = o.y * ia, anz = o.z * ia, anw = o.w * ia;
  const float vnx = vv.x * iv, vny = vv.y * iv, vnz = vv.z * iv, vnw = vv.w * iv;
  u16* xr = xb + (size_t)row * 768;
  u32 pa[2] = {pkbf(anx, any_), pkbf(anz, anw)};
  u32 pv[2] = {pkbf(vnx, vny), pkbf(vnz, vnw)};
  u32 pp[2] = {pkbf(anx * vnx, any_ * vny), pkbf(anz * vnz, anw * vnw)};
  *(uint2*)&xr[d4] = *(uint2*)pa;
  *(uint2*)&xr[256 + d4] = *(uint2*)pv;
  *(uint2*)&xr[512 + d4] = *(uint2*)pp;
}

// ---------- gate + mix ----------
__global__ __launch_bounds__(256) void gate_mix(const float* __restrict__ logits,
                                                const float* __restrict__ b2,
                                                const float* __restrict__ actx,
                                                const float* __restrict__ v,
                                                float* __restrict__ out) {
  const int row = blockIdx.x * 4 + (threadIdx.x >> 6);
  const int lane = threadIdx.x & 63;
  const float l = fminf(fmaxf(logits[row] + b2[0], -12.0f), 12.0f);
  float g = 1.0f / (1.0f + expf(-l));
  g = fminf(fmaxf(g, 0.05f), 0.95f);
  const float4 aa = *(const float4*)&actx[(size_t)row * 256 + lane * 4];
  const float4 vv = *(const float4*)&v[(size_t)row * 256 + lane * 4];
  float4 o;
  o.x = g * aa.x + (1.0f - g) * vv.x;
  o.y = g * aa.y + (1.0f - g) * vv.y;
  o.z = g * aa.z + (1.0f - g) * vv.z;
  o.w = g * aa.w + (1.0f - g) * vv.w;
  *(float4*)&out[(size_t)row * 256 + lane * 4] = o;
}

// ---------- launch ----------
extern "C" void kernel_launch(void* const* d_in, const int* in_sizes, int n_in,
                              void* d_out, int out_size, void* d_ws, size_t ws_size,
                              hipStream_t stream) {
  const float* video = (const float*)d_in[0];
  const float* audio = (const float*)d_in[1];
  const float* Wv    = (const float*)d_in[2];
  const float* bv    = (const float*)d_in[3];
  const float* Wa    = (const float*)d_in[4];
  const float* ba    = (const float*)d_in[5];
  const float* theta = (const float*)d_in[6];
  const float* W1    = (const float*)d_in[7];
  const float* b1    = (const float*)d_in[8];
  const float* W2    = (const float*)d_in[9];
  const float* b2    = (const float*)d_in[10];
  float* out = (float*)d_out;
  char* ws = (char*)d_ws;

  const size_t OFF_WVT = 0;          // [256][1024] bf16 = 512 KB
  const size_t OFF_WAT = 524288;     // [256][768]  bf16 = 384 KB
  const size_t OFF_W1T = 917504;     // [1024][768] bf16 = 1.5 MB
  const size_t OFF_LOG = 2490368;    // [16384] f32 = 64 KB
  const size_t OFF_V   = 2555904;    // [16384][256] f32 = 16 MB (LN'd v)
  const size_t OFF_A   = 19333120;   // [16384][256] f32 = 16 MB (LN'd a)
  const size_t OFF_ACTX= 36110336;   // [16384][256] f32 = 16 MB
  const size_t OFF_XB  = 52887552;   // [16384][768] bf16 = 24 MB

  u16* wvT = (u16*)(ws + OFF_WVT);
  u16* waT = (u16*)(ws + OFF_WAT);
  u16* w1T = (u16*)(ws + OFF_W1T);
  float* logits = (float*)(ws + OFF_LOG);
  float* v    = (float*)(ws + OFF_V);
  float* a    = (float*)(ws + OFF_A);
  float* actx = (float*)(ws + OFF_ACTX);
  u16* xb = (u16*)(ws + OFF_XB);

  tcvt_all<<<1280, 256, 0, stream>>>(Wv, Wa, W1, wvT, waT, w1T, logits);
  proj_ln<<<512, 256, 0, stream>>>(video, audio, wvT, waT, bv, ba, v, a);
  shift_norm<<<BT_ROWS / 4, 256, 0, stream>>>(a, v, actx, xb, theta);
  gemm_gelu_w2<<<dim3(8, BT_ROWS / 128), 256, 0, stream>>>(xb, w1T, b1, W2, logits);
  gate_mix<<<BT_ROWS / 4, 256, 0, stream>>>(logits, b2, actx, v, out);
}